// Round 1
// baseline (579.844 us; speedup 1.0000x reference)
//
#include <hip/hip_runtime.h>
#include <math.h>

#define NN 100000
#define EE 800000
#define FDIM 64
#define NH 4
#define HO 256            // NH * FDIM
#define NEG 0.2f

#define SCAN_BLK 1024
#define SCAN_NBLK 98      // ceil(100000/1024)

// ---------- workspace layout (bytes) ----------
#define OFF_H      0ull                       // bf16 h: N*256*2 = 51,200,000
#define OFF_HOP1   0ull                       // aliases h (h dead when hops run)
#define OFF_HOP2   25600000ull
#define OFF_SSRC   51200000ull                // N*4 fp32 = 1,600,000
#define OFF_SDST   52800000ull
#define OFF_DEGC   54400000ull                // N int
#define OFF_ROWS   54800000ull
#define OFF_CURS   55200000ull
#define OFF_DEGF   55600000ull
#define OFF_PART   56000000ull                // scan partials
#define OFF_CSRS   56001024ull                // E int = 3,200,000
#define OFF_WCOMB  59201024ull                // 64*64 fp32
#define OFF_BCOMB  59217408ull                // 64 fp32
#define WS_NEEDED  59217664ull

__device__ __forceinline__ float bf2f(unsigned int u16) {
    return __uint_as_float(u16 << 16);
}
__device__ __forceinline__ unsigned short f2bf(float f) {
    unsigned int u = __float_as_uint(f);
    unsigned int r = u + 0x7fffu + ((u >> 16) & 1u);   // RNE
    return (unsigned short)(r >> 16);
}
__device__ __forceinline__ float lrelu(float x) { return x > 0.f ? x : NEG * x; }

// ---------- K1: h = x @ W_att (per head), fused s_src/s_dst ----------
__global__ __launch_bounds__(256) void k_h(
    const float* __restrict__ x, const float* __restrict__ Watt,
    const float* __restrict__ asrc, const float* __restrict__ adst,
    unsigned short* __restrict__ hb, float* __restrict__ ssrc, float* __restrict__ sdst)
{
    __shared__ float xs[16 * 64];
    const int t = threadIdx.x;
    const int n0 = blockIdx.x * 16;
#pragma unroll
    for (int k = 0; k < 4; k++) xs[t + k * 256] = x[(size_t)n0 * 64 + t + k * 256];
    __syncthreads();
    const int hh = t >> 6, oo = t & 63;
    float acc[16];
#pragma unroll
    for (int i = 0; i < 16; i++) acc[i] = 0.f;
    const float* wc = Watt + hh * 4096 + oo;
    for (int i = 0; i < 64; i += 4) {
        float w0 = wc[(i + 0) * 64], w1 = wc[(i + 1) * 64];
        float w2 = wc[(i + 2) * 64], w3 = wc[(i + 3) * 64];
#pragma unroll
        for (int nl = 0; nl < 16; nl++) {
            const float4 xv = *(const float4*)&xs[nl * 64 + i];
            acc[nl] += xv.x * w0 + xv.y * w1 + xv.z * w2 + xv.w * w3;
        }
    }
    const float as = asrc[hh * 64 + oo], ad = adst[hh * 64 + oo];
#pragma unroll
    for (int nl = 0; nl < 16; nl++) {
        hb[(size_t)(n0 + nl) * HO + t] = f2bf(acc[nl]);
        float ps = acc[nl] * as, pd = acc[nl] * ad;
#pragma unroll
        for (int off = 1; off < 64; off <<= 1) {
            ps += __shfl_xor(ps, off);
            pd += __shfl_xor(pd, off);
        }
        if ((t & 63) == 0) {
            ssrc[(n0 + nl) * 4 + hh] = ps;
            sdst[(n0 + nl) * 4 + hh] = pd;
        }
    }
}

// ---------- K2: in-degree histogram ----------
__global__ void k_hist(const int* __restrict__ dst, int* __restrict__ degc) {
    int e = blockIdx.x * 256 + threadIdx.x;
    if (e < EE) atomicAdd(&degc[dst[e]], 1);
}

// ---------- K3: 3-kernel exclusive scan ----------
__global__ __launch_bounds__(1024) void k_scan_a(const int* __restrict__ degc, int* __restrict__ part) {
    __shared__ int sh[1024];
    int t = threadIdx.x;
    int i = blockIdx.x * SCAN_BLK + t;
    sh[t] = (i < NN) ? degc[i] : 0;
    __syncthreads();
    for (int off = 512; off > 0; off >>= 1) {
        if (t < off) sh[t] += sh[t + off];
        __syncthreads();
    }
    if (t == 0) part[blockIdx.x] = sh[0];
}

__global__ __launch_bounds__(128) void k_scan_b(int* part) {
    __shared__ int sh[128];
    int t = threadIdx.x;
    int v = (t < SCAN_NBLK) ? part[t] : 0;
    sh[t] = v;
    __syncthreads();
    for (int off = 1; off < 128; off <<= 1) {
        int tmp = (t >= off) ? sh[t - off] : 0;
        __syncthreads();
        sh[t] += tmp;
        __syncthreads();
    }
    if (t < SCAN_NBLK) part[t] = sh[t] - v;   // exclusive
}

__global__ __launch_bounds__(1024) void k_scan_c(
    const int* __restrict__ degc, const int* __restrict__ part,
    int* __restrict__ rows, int* __restrict__ curs, float* __restrict__ degf)
{
    __shared__ int sh[1024];
    int t = threadIdx.x;
    int i = blockIdx.x * SCAN_BLK + t;
    int v = (i < NN) ? degc[i] : 0;
    sh[t] = v;
    __syncthreads();
    for (int off = 1; off < 1024; off <<= 1) {
        int tmp = (t >= off) ? sh[t - off] : 0;
        __syncthreads();
        sh[t] += tmp;
        __syncthreads();
    }
    int excl = sh[t] - v + part[blockIdx.x];
    if (i < NN) {
        rows[i] = excl;
        curs[i] = excl;
        degf[i] = (float)max(v, 1);
    }
}

// ---------- K4: scatter edges into CSR (by dst) ----------
__global__ void k_scatter(const int* __restrict__ src, const int* __restrict__ dst,
                          int* __restrict__ curs, int* __restrict__ csrs) {
    int e = blockIdx.x * 256 + threadIdx.x;
    if (e < EE) {
        int d = dst[e];
        int pos = atomicAdd(&curs[d], 1);
        csrs[pos] = src[e];
    }
}

// ---------- K5: attention softmax + aggregate (one wave per dst node) ----------
__global__ __launch_bounds__(256) void k_attn(
    const unsigned short* __restrict__ hb,
    const float* __restrict__ ssrc, const float* __restrict__ sdst,
    const int* __restrict__ rows, const int* __restrict__ degc,
    const int* __restrict__ csrs, float* __restrict__ local)
{
    const int lane = threadIdx.x & 63;
    const int n = blockIdx.x * 4 + (threadIdx.x >> 6);
    if (n >= NN) return;
    const int start = rows[n], cnt = degc[n];
    float4 acc = {0.f, 0.f, 0.f, 0.f};
    if (cnt > 0) {
        const float sd0 = sdst[n * 4 + 0], sd1 = sdst[n * 4 + 1];
        const float sd2 = sdst[n * 4 + 2], sd3 = sdst[n * 4 + 3];
        // pass 1: per-lane online (m, den)
        float m0 = -1e30f, m1 = -1e30f, m2 = -1e30f, m3 = -1e30f;
        float d0 = 0.f, d1 = 0.f, d2 = 0.f, d3 = 0.f;
        for (int base = 0; base < cnt; base += 64) {
            int j = base + lane;
            if (j < cnt) {
                int s = csrs[start + j];
                float4 ss = *(const float4*)&ssrc[s * 4];
                float e0 = lrelu(ss.x + sd0), e1 = lrelu(ss.y + sd1);
                float e2 = lrelu(ss.z + sd2), e3 = lrelu(ss.w + sd3);
                float nm;
                nm = fmaxf(m0, e0); d0 = d0 * __expf(m0 - nm) + __expf(e0 - nm); m0 = nm;
                nm = fmaxf(m1, e1); d1 = d1 * __expf(m1 - nm) + __expf(e1 - nm); m1 = nm;
                nm = fmaxf(m2, e2); d2 = d2 * __expf(m2 - nm) + __expf(e2 - nm); m2 = nm;
                nm = fmaxf(m3, e3); d3 = d3 * __expf(m3 - nm) + __expf(e3 - nm); m3 = nm;
            }
        }
        // cross-lane merge of (m, den)
#pragma unroll
        for (int off = 1; off < 64; off <<= 1) {
            float mo, dn, nm;
            mo = __shfl_xor(m0, off); dn = __shfl_xor(d0, off);
            nm = fmaxf(m0, mo); d0 = d0 * __expf(m0 - nm) + dn * __expf(mo - nm); m0 = nm;
            mo = __shfl_xor(m1, off); dn = __shfl_xor(d1, off);
            nm = fmaxf(m1, mo); d1 = d1 * __expf(m1 - nm) + dn * __expf(mo - nm); m1 = nm;
            mo = __shfl_xor(m2, off); dn = __shfl_xor(d2, off);
            nm = fmaxf(m2, mo); d2 = d2 * __expf(m2 - nm) + dn * __expf(mo - nm); m2 = nm;
            mo = __shfl_xor(m3, off); dn = __shfl_xor(d3, off);
            nm = fmaxf(m3, mo); d3 = d3 * __expf(m3 - nm) + dn * __expf(mo - nm); m3 = nm;
        }
        const float i0 = 1.f / fmaxf(d0, 1e-16f), i1 = 1.f / fmaxf(d1, 1e-16f);
        const float i2 = 1.f / fmaxf(d2, 1e-16f), i3 = 1.f / fmaxf(d3, 1e-16f);
        const int hh = lane >> 4;
        // pass 2: alpha-weighted gather of h[src] rows
        for (int base = 0; base < cnt; base += 64) {
            int j = base + lane;
            float a0 = 0.f, a1 = 0.f, a2 = 0.f, a3 = 0.f;
            int sj = 0;
            if (j < cnt) {
                sj = csrs[start + j];
                float4 ss = *(const float4*)&ssrc[sj * 4];
                a0 = __expf(lrelu(ss.x + sd0) - m0) * i0;
                a1 = __expf(lrelu(ss.y + sd1) - m1) * i1;
                a2 = __expf(lrelu(ss.z + sd2) - m2) * i2;
                a3 = __expf(lrelu(ss.w + sd3) - m3) * i3;
            }
            int lim = min(64, cnt - base);
            for (int jj = 0; jj < lim; jj++) {
                int s = __shfl(sj, jj);
                float ax = __shfl(a0, jj), ay = __shfl(a1, jj);
                float az = __shfl(a2, jj), aw = __shfl(a3, jj);
                float a = (hh == 0) ? ax : (hh == 1) ? ay : (hh == 2) ? az : aw;
                uint2 u = *(const uint2*)&hb[(size_t)s * HO + lane * 4];
                acc.x += a * bf2f(u.x & 0xffffu);
                acc.y += a * bf2f(u.x >> 16);
                acc.z += a * bf2f(u.y & 0xffffu);
                acc.w += a * bf2f(u.y >> 16);
            }
        }
    }
    // mean over heads: lanes {l, l^16, l^32, l^48} hold same within-head cols
#pragma unroll
    for (int off = 16; off < 64; off <<= 1) {
        acc.x += __shfl_xor(acc.x, off);
        acc.y += __shfl_xor(acc.y, off);
        acc.z += __shfl_xor(acc.z, off);
        acc.w += __shfl_xor(acc.w, off);
    }
    if (lane < 16) {
        float4 o = {acc.x * 0.25f, acc.y * 0.25f, acc.z * 0.25f, acc.w * 0.25f};
        *(float4*)&local[(size_t)n * 64 + lane * 4] = o;
    }
}

// ---------- K6/K7: one mean-aggregation hop (wave per node) ----------
__global__ __launch_bounds__(256) void k_hop(
    const float* __restrict__ xin, const int* __restrict__ rows,
    const int* __restrict__ degc, const float* __restrict__ degf,
    const int* __restrict__ csrs, float* __restrict__ outp)
{
    const int lane = threadIdx.x & 63;
    const int n = blockIdx.x * 4 + (threadIdx.x >> 6);
    if (n >= NN) return;
    const int start = rows[n], cnt = degc[n];
    float acc = 0.f;
    int j = 0;
    for (; j + 4 <= cnt; j += 4) {
        int s0 = csrs[start + j], s1 = csrs[start + j + 1];
        int s2 = csrs[start + j + 2], s3 = csrs[start + j + 3];
        acc += xin[(size_t)s0 * 64 + lane] + xin[(size_t)s1 * 64 + lane] +
               xin[(size_t)s2 * 64 + lane] + xin[(size_t)s3 * 64 + lane];
    }
    for (; j < cnt; j++) {
        int s = csrs[start + j];
        acc += xin[(size_t)s * 64 + lane];
    }
    outp[(size_t)n * 64 + lane] = acc / degf[n];
}

// ---------- K8: fold W_g / b_g through W_w bottom half ----------
__global__ __launch_bounds__(64) void k_wcomb(
    const float* __restrict__ Wg, const float* __restrict__ bg,
    const float* __restrict__ Ww, const float* __restrict__ bw,
    float* __restrict__ Wc, float* __restrict__ bc)
{
    int c = threadIdx.x;
    int b = blockIdx.x;
    if (b < 64) {
        float a = 0.f;
        for (int m = 0; m < 64; m++) a += Wg[b * 64 + m] * Ww[(64 + m) * 64 + c];
        Wc[b * 64 + c] = a;
    } else {
        float a = bw[c];
        for (int m = 0; m < 64; m++) a += bg[m] * Ww[(64 + m) * 64 + c];
        bc[c] = a;
    }
}

// ---------- K9: out = local @ Ww_top + hop2 @ Wc + bc  (in-place on d_out) ----------
__global__ __launch_bounds__(256) void k_final(
    const float* __restrict__ Ww, const float* __restrict__ Wc,
    const float* __restrict__ bc, const float* __restrict__ hop2,
    float* __restrict__ outp)
{
    __shared__ float W1s[64 * 64];
    __shared__ float Wcs[64 * 64];
    __shared__ float lr[4 * 64];
    __shared__ float gr[4 * 64];
    const int t = threadIdx.x;
    const int n0 = blockIdx.x * 4;
#pragma unroll
    for (int k = 0; k < 16; k++) {
        W1s[t + k * 256] = Ww[t + k * 256];       // first 64 rows of [128,64]
        Wcs[t + k * 256] = Wc[t + k * 256];
    }
    lr[t] = outp[(size_t)n0 * 64 + t];
    gr[t] = hop2[(size_t)n0 * 64 + t];
    __syncthreads();
    const int nl = t >> 6, c = t & 63;
    float a = bc[c];
    for (int k = 0; k < 64; k += 4) {
        a += lr[nl * 64 + k + 0] * W1s[(k + 0) * 64 + c] + gr[nl * 64 + k + 0] * Wcs[(k + 0) * 64 + c];
        a += lr[nl * 64 + k + 1] * W1s[(k + 1) * 64 + c] + gr[nl * 64 + k + 1] * Wcs[(k + 1) * 64 + c];
        a += lr[nl * 64 + k + 2] * W1s[(k + 2) * 64 + c] + gr[nl * 64 + k + 2] * Wcs[(k + 2) * 64 + c];
        a += lr[nl * 64 + k + 3] * W1s[(k + 3) * 64 + c] + gr[nl * 64 + k + 3] * Wcs[(k + 3) * 64 + c];
    }
    outp[(size_t)(n0 + nl) * 64 + c] = a;
}

extern "C" void kernel_launch(void* const* d_in, const int* in_sizes, int n_in,
                              void* d_out, int out_size, void* d_ws, size_t ws_size,
                              hipStream_t stream)
{
    const float* x    = (const float*)d_in[0];
    const int*   ei   = (const int*)d_in[1];
    const int*   srcp = ei;
    const int*   dstp = ei + EE;
    const float* Watt = (const float*)d_in[2];
    const float* asrc = (const float*)d_in[3];
    const float* adst = (const float*)d_in[4];
    const float* Wg   = (const float*)d_in[5];
    const float* bg   = (const float*)d_in[6];
    const float* Ww   = (const float*)d_in[7];
    const float* bw   = (const float*)d_in[8];
    float* outp = (float*)d_out;

    if (ws_size < WS_NEEDED) return;   // fail loudly (validation will catch)

    char* ws = (char*)d_ws;
    unsigned short* hb = (unsigned short*)(ws + OFF_H);
    float* hop1 = (float*)(ws + OFF_HOP1);     // aliases hb (dead by then)
    float* hop2 = (float*)(ws + OFF_HOP2);
    float* ssrc = (float*)(ws + OFF_SSRC);
    float* sdst = (float*)(ws + OFF_SDST);
    int*   degc = (int*)(ws + OFF_DEGC);
    int*   rows = (int*)(ws + OFF_ROWS);
    int*   curs = (int*)(ws + OFF_CURS);
    float* degf = (float*)(ws + OFF_DEGF);
    int*   part = (int*)(ws + OFF_PART);
    int*   csrs = (int*)(ws + OFF_CSRS);
    float* Wc   = (float*)(ws + OFF_WCOMB);
    float* bc   = (float*)(ws + OFF_BCOMB);

    hipMemsetAsync(degc, 0, NN * sizeof(int), stream);
    k_hist<<<(EE + 255) / 256, 256, 0, stream>>>(dstp, degc);
    k_scan_a<<<SCAN_NBLK, 1024, 0, stream>>>(degc, part);
    k_scan_b<<<1, 128, 0, stream>>>(part);
    k_scan_c<<<SCAN_NBLK, 1024, 0, stream>>>(degc, part, rows, curs, degf);
    k_scatter<<<(EE + 255) / 256, 256, 0, stream>>>(srcp, dstp, curs, csrs);
    k_h<<<NN / 16, 256, 0, stream>>>(x, Watt, asrc, adst, hb, ssrc, sdst);
    k_attn<<<NN / 4, 256, 0, stream>>>(hb, ssrc, sdst, rows, degc, csrs, outp);
    k_hop<<<NN / 4, 256, 0, stream>>>(x, rows, degc, degf, csrs, hop1);
    k_hop<<<NN / 4, 256, 0, stream>>>(hop1, rows, degc, degf, csrs, hop2);
    k_wcomb<<<65, 64, 0, stream>>>(Wg, bg, Ww, bw, Wc, bc);
    k_final<<<NN / 4, 256, 0, stream>>>(Ww, Wc, bc, hop2, outp);
}

// Round 2
// 573.686 us; speedup vs baseline: 1.0107x; 1.0107x over previous
//
#include <hip/hip_runtime.h>
#include <math.h>

#define NN 100000
#define EE 800000
#define FDIM 64
#define NH 4
#define HO 256            // NH * FDIM
#define NEG 0.2f

#define SCAN_BLK 1024
#define SCAN_NBLK 98      // ceil(100000/1024)

// ---------- workspace layout (bytes) ----------
#define OFF_H      0ull                       // bf16 h: N*256*2 = 51,200,000
#define OFF_HOP1   0ull                       // bf16 hop1 (12.8 MB) aliases h (dead after attn)
#define OFF_HOP2   12800000ull                // fp32 hop2 (25.6 MB), also inside dead h
#define OFF_XB     51200000ull                // bf16 x: 12.8 MB
#define OFF_SSRC   64000000ull                // N*4 fp32
#define OFF_SDST   65600000ull
#define OFF_DEGC   67200000ull                // N int
#define OFF_ROWS   67600000ull
#define OFF_CURS   68000000ull
#define OFF_DEGF   68400000ull
#define OFF_PART   68800000ull
#define OFF_CSRS   68801024ull                // E int
#define OFF_WCOMB  72001024ull
#define OFF_BCOMB  72017408ull
#define WS_NEEDED  72017664ull

__device__ __forceinline__ float bflo(unsigned int u) { return __uint_as_float(u << 16); }
__device__ __forceinline__ float bfhi(unsigned int u) { return __uint_as_float(u & 0xffff0000u); }
__device__ __forceinline__ unsigned short f2bf(float f) {
    unsigned int u = __float_as_uint(f);
    unsigned int r = u + 0x7fffu + ((u >> 16) & 1u);   // RNE
    return (unsigned short)(r >> 16);
}
__device__ __forceinline__ float lrelu(float x) { return x > 0.f ? x : NEG * x; }

// ---------- K1: h = x @ W_att (per head), fused s_src/s_dst, + x->bf16 ----------
__global__ __launch_bounds__(256) void k_h(
    const float* __restrict__ x, const float* __restrict__ Watt,
    const float* __restrict__ asrc, const float* __restrict__ adst,
    unsigned short* __restrict__ hb, unsigned short* __restrict__ xb,
    float* __restrict__ ssrc, float* __restrict__ sdst)
{
    __shared__ float xs[16 * 64];
    const int t = threadIdx.x;
    const int n0 = blockIdx.x * 16;
#pragma unroll
    for (int k = 0; k < 4; k++) xs[t + k * 256] = x[(size_t)n0 * 64 + t + k * 256];
    __syncthreads();
    // emit bf16 copy of x (for hop gathers): thread t packs elements 4t..4t+3
    {
        const int i4 = t * 4;
        uint2 p;
        p.x = (unsigned int)f2bf(xs[i4]) | ((unsigned int)f2bf(xs[i4 + 1]) << 16);
        p.y = (unsigned int)f2bf(xs[i4 + 2]) | ((unsigned int)f2bf(xs[i4 + 3]) << 16);
        *(uint2*)&xb[(size_t)n0 * 64 + i4] = p;
    }
    const int hh = t >> 6, oo = t & 63;
    float acc[16];
#pragma unroll
    for (int i = 0; i < 16; i++) acc[i] = 0.f;
    const float* wc = Watt + hh * 4096 + oo;
    for (int i = 0; i < 64; i += 4) {
        float w0 = wc[(i + 0) * 64], w1 = wc[(i + 1) * 64];
        float w2 = wc[(i + 2) * 64], w3 = wc[(i + 3) * 64];
#pragma unroll
        for (int nl = 0; nl < 16; nl++) {
            const float4 xv = *(const float4*)&xs[nl * 64 + i];
            acc[nl] += xv.x * w0 + xv.y * w1 + xv.z * w2 + xv.w * w3;
        }
    }
    const float as = asrc[hh * 64 + oo], ad = adst[hh * 64 + oo];
#pragma unroll
    for (int nl = 0; nl < 16; nl++) {
        hb[(size_t)(n0 + nl) * HO + t] = f2bf(acc[nl]);
        float ps = acc[nl] * as, pd = acc[nl] * ad;
#pragma unroll
        for (int off = 1; off < 64; off <<= 1) {
            ps += __shfl_xor(ps, off);
            pd += __shfl_xor(pd, off);
        }
        if ((t & 63) == 0) {
            ssrc[(n0 + nl) * 4 + hh] = ps;
            sdst[(n0 + nl) * 4 + hh] = pd;
        }
    }
}

// ---------- K2: in-degree histogram ----------
__global__ void k_hist(const int* __restrict__ dst, int* __restrict__ degc) {
    int e = blockIdx.x * 256 + threadIdx.x;
    if (e < EE) atomicAdd(&degc[dst[e]], 1);
}

// ---------- K3: 3-kernel exclusive scan ----------
__global__ __launch_bounds__(1024) void k_scan_a(const int* __restrict__ degc, int* __restrict__ part) {
    __shared__ int sh[1024];
    int t = threadIdx.x;
    int i = blockIdx.x * SCAN_BLK + t;
    sh[t] = (i < NN) ? degc[i] : 0;
    __syncthreads();
    for (int off = 512; off > 0; off >>= 1) {
        if (t < off) sh[t] += sh[t + off];
        __syncthreads();
    }
    if (t == 0) part[blockIdx.x] = sh[0];
}

__global__ __launch_bounds__(128) void k_scan_b(int* part) {
    __shared__ int sh[128];
    int t = threadIdx.x;
    int v = (t < SCAN_NBLK) ? part[t] : 0;
    sh[t] = v;
    __syncthreads();
    for (int off = 1; off < 128; off <<= 1) {
        int tmp = (t >= off) ? sh[t - off] : 0;
        __syncthreads();
        sh[t] += tmp;
        __syncthreads();
    }
    if (t < SCAN_NBLK) part[t] = sh[t] - v;   // exclusive
}

__global__ __launch_bounds__(1024) void k_scan_c(
    const int* __restrict__ degc, const int* __restrict__ part,
    int* __restrict__ rows, int* __restrict__ curs, float* __restrict__ degf)
{
    __shared__ int sh[1024];
    int t = threadIdx.x;
    int i = blockIdx.x * SCAN_BLK + t;
    int v = (i < NN) ? degc[i] : 0;
    sh[t] = v;
    __syncthreads();
    for (int off = 1; off < 1024; off <<= 1) {
        int tmp = (t >= off) ? sh[t - off] : 0;
        __syncthreads();
        sh[t] += tmp;
        __syncthreads();
    }
    int excl = sh[t] - v + part[blockIdx.x];
    if (i < NN) {
        rows[i] = excl;
        curs[i] = excl;
        degf[i] = (float)max(v, 1);
    }
}

// ---------- K4: scatter edges into CSR (by dst) ----------
__global__ void k_scatter(const int* __restrict__ src, const int* __restrict__ dst,
                          int* __restrict__ curs, int* __restrict__ csrs) {
    int e = blockIdx.x * 256 + threadIdx.x;
    if (e < EE) {
        int d = dst[e];
        int pos = atomicAdd(&curs[d], 1);
        csrs[pos] = src[e];
    }
}

// ---------- K5: attention (one wave per dst node, no-max softmax, single pass) ----
// lane = hh*16 + c: lane group hh handles head hh; edge slot c within 16-edge chunk.
// acc identity: sum_j alpha_j h_j = (sum_j ex_j h_j) / den  -> scale once at end.
__global__ __launch_bounds__(256) void k_attn(
    const unsigned short* __restrict__ hb,
    const float* __restrict__ ssrc, const float* __restrict__ sdst,
    const int* __restrict__ rows, const int* __restrict__ degc,
    const int* __restrict__ csrs, float* __restrict__ local)
{
    const int lane = threadIdx.x & 63;
    const int n = blockIdx.x * 4 + (threadIdx.x >> 6);
    if (n >= NN) return;
    const int start = rows[n], cnt = degc[n];
    const int hh = lane >> 4, c = lane & 15;
    const int permbase = (lane & 48) * 4;   // byte index base for bpermute within head group
    float4 acc = {0.f, 0.f, 0.f, 0.f};
    if (cnt > 0) {
        const float4 sd = *(const float4*)&sdst[n * 4];
        float den = 0.f;
        for (int base = 0; base < cnt; base += 16) {
            const int j = base + c;
            int sj = 0; float exsel = 0.f;
            if (j < cnt) {
                sj = csrs[start + j];
                const float4 ss = *(const float4*)&ssrc[sj * 4];
                const float e0 = __expf(lrelu(ss.x + sd.x));
                const float e1 = __expf(lrelu(ss.y + sd.y));
                const float e2 = __expf(lrelu(ss.z + sd.z));
                const float e3 = __expf(lrelu(ss.w + sd.w));
                exsel = (hh == 0) ? e0 : (hh == 1) ? e1 : (hh == 2) ? e2 : e3;
            }
            den += exsel;
            const int lim = min(16, cnt - base);
            for (int jj = 0; jj < lim; jj++) {
                const int   s = __shfl(sj,    (permbase >> 2) + jj);
                const float a = __shfl(exsel, (permbase >> 2) + jj);
                const uint2 u = *(const uint2*)&hb[(size_t)s * HO + lane * 4];
                acc.x += a * bflo(u.x);
                acc.y += a * bfhi(u.x);
                acc.z += a * bflo(u.y);
                acc.w += a * bfhi(u.y);
            }
        }
        // den: sum within each 16-lane head group
        den += __shfl_xor(den, 1);
        den += __shfl_xor(den, 2);
        den += __shfl_xor(den, 4);
        den += __shfl_xor(den, 8);
        const float inv = 1.f / den;   // den > 0 (cnt>0, exp>0)
        acc.x *= inv; acc.y *= inv; acc.z *= inv; acc.w *= inv;
    }
    // mean over heads: groups {hh} hold same columns -> butterfly over xor 16,32
#pragma unroll
    for (int off = 16; off < 64; off <<= 1) {
        acc.x += __shfl_xor(acc.x, off);
        acc.y += __shfl_xor(acc.y, off);
        acc.z += __shfl_xor(acc.z, off);
        acc.w += __shfl_xor(acc.w, off);
    }
    if (lane < 16) {
        float4 o = {acc.x * 0.25f, acc.y * 0.25f, acc.z * 0.25f, acc.w * 0.25f};
        *(float4*)&local[(size_t)n * 64 + lane * 4] = o;
    }
}

// ---------- K6/K7: one mean-aggregation hop, bf16 gather (wave per node) --------
// half-wave per edge: lanes 0-31 handle even edges, 32-63 odd. Lane covers 2 cols.
__global__ __launch_bounds__(256) void k_hop(
    const unsigned short* __restrict__ xin, const int* __restrict__ rows,
    const int* __restrict__ degc, const float* __restrict__ degf,
    const int* __restrict__ csrs,
    unsigned short* __restrict__ out_b, float* __restrict__ out_f, int out_fp32)
{
    const int lane = threadIdx.x & 63;
    const int n = blockIdx.x * 4 + (threadIdx.x >> 6);
    if (n >= NN) return;
    const int start = rows[n], cnt = degc[n];
    const int half = lane >> 5, c = lane & 31;
    float a0 = 0.f, a1 = 0.f;
    for (int j = half; j < cnt; j += 2) {
        const int s = csrs[start + j];
        const unsigned int u = *(const unsigned int*)&xin[(size_t)s * 64 + c * 2];
        a0 += bflo(u);
        a1 += bfhi(u);
    }
    a0 += __shfl_xor(a0, 32);
    a1 += __shfl_xor(a1, 32);
    if (lane < 32) {
        const float inv = 1.f / degf[n];
        a0 *= inv; a1 *= inv;
        if (out_fp32) {
            float2 o = {a0, a1};
            *(float2*)&out_f[(size_t)n * 64 + c * 2] = o;
        } else {
            unsigned int p = (unsigned int)f2bf(a0) | ((unsigned int)f2bf(a1) << 16);
            *(unsigned int*)&out_b[(size_t)n * 64 + c * 2] = p;
        }
    }
}

// ---------- K8: fold W_g / b_g through W_w bottom half ----------
__global__ __launch_bounds__(64) void k_wcomb(
    const float* __restrict__ Wg, const float* __restrict__ bg,
    const float* __restrict__ Ww, const float* __restrict__ bw,
    float* __restrict__ Wc, float* __restrict__ bc)
{
    int c = threadIdx.x;
    int b = blockIdx.x;
    if (b < 64) {
        float a = 0.f;
        for (int m = 0; m < 64; m++) a += Wg[b * 64 + m] * Ww[(64 + m) * 64 + c];
        Wc[b * 64 + c] = a;
    } else {
        float a = bw[c];
        for (int m = 0; m < 64; m++) a += bg[m] * Ww[(64 + m) * 64 + c];
        bc[c] = a;
    }
}

// ---------- K9: out = local @ Ww_top + hop2 @ Wc + bc  (in-place on d_out) ----------
__global__ __launch_bounds__(256) void k_final(
    const float* __restrict__ Ww, const float* __restrict__ Wc,
    const float* __restrict__ bc, const float* __restrict__ hop2,
    float* __restrict__ outp)
{
    __shared__ float W1s[64 * 64];
    __shared__ float Wcs[64 * 64];
    __shared__ float lr[4 * 64];
    __shared__ float gr[4 * 64];
    const int t = threadIdx.x;
    const int n0 = blockIdx.x * 4;
#pragma unroll
    for (int k = 0; k < 16; k++) {
        W1s[t + k * 256] = Ww[t + k * 256];       // first 64 rows of [128,64]
        Wcs[t + k * 256] = Wc[t + k * 256];
    }
    lr[t] = outp[(size_t)n0 * 64 + t];
    gr[t] = hop2[(size_t)n0 * 64 + t];
    __syncthreads();
    const int nl = t >> 6, c = t & 63;
    float a = bc[c];
    for (int k = 0; k < 64; k += 4) {
        a += lr[nl * 64 + k + 0] * W1s[(k + 0) * 64 + c] + gr[nl * 64 + k + 0] * Wcs[(k + 0) * 64 + c];
        a += lr[nl * 64 + k + 1] * W1s[(k + 1) * 64 + c] + gr[nl * 64 + k + 1] * Wcs[(k + 1) * 64 + c];
        a += lr[nl * 64 + k + 2] * W1s[(k + 2) * 64 + c] + gr[nl * 64 + k + 2] * Wcs[(k + 2) * 64 + c];
        a += lr[nl * 64 + k + 3] * W1s[(k + 3) * 64 + c] + gr[nl * 64 + k + 3] * Wcs[(k + 3) * 64 + c];
    }
    outp[(size_t)(n0 + nl) * 64 + c] = a;
}

extern "C" void kernel_launch(void* const* d_in, const int* in_sizes, int n_in,
                              void* d_out, int out_size, void* d_ws, size_t ws_size,
                              hipStream_t stream)
{
    const float* x    = (const float*)d_in[0];
    const int*   ei   = (const int*)d_in[1];
    const int*   srcp = ei;
    const int*   dstp = ei + EE;
    const float* Watt = (const float*)d_in[2];
    const float* asrc = (const float*)d_in[3];
    const float* adst = (const float*)d_in[4];
    const float* Wg   = (const float*)d_in[5];
    const float* bg   = (const float*)d_in[6];
    const float* Ww   = (const float*)d_in[7];
    const float* bw   = (const float*)d_in[8];
    float* outp = (float*)d_out;

    if (ws_size < WS_NEEDED) return;   // fail loudly (validation will catch)

    char* ws = (char*)d_ws;
    unsigned short* hb   = (unsigned short*)(ws + OFF_H);
    unsigned short* hop1 = (unsigned short*)(ws + OFF_HOP1);  // aliases hb (dead)
    float*          hop2 = (float*)(ws + OFF_HOP2);           // inside dead hb too
    unsigned short* xb   = (unsigned short*)(ws + OFF_XB);
    float* ssrc = (float*)(ws + OFF_SSRC);
    float* sdst = (float*)(ws + OFF_SDST);
    int*   degc = (int*)(ws + OFF_DEGC);
    int*   rows = (int*)(ws + OFF_ROWS);
    int*   curs = (int*)(ws + OFF_CURS);
    float* degf = (float*)(ws + OFF_DEGF);
    int*   part = (int*)(ws + OFF_PART);
    int*   csrs = (int*)(ws + OFF_CSRS);
    float* Wc   = (float*)(ws + OFF_WCOMB);
    float* bc   = (float*)(ws + OFF_BCOMB);

    hipMemsetAsync(degc, 0, NN * sizeof(int), stream);
    k_hist<<<(EE + 255) / 256, 256, 0, stream>>>(dstp, degc);
    k_scan_a<<<SCAN_NBLK, 1024, 0, stream>>>(degc, part);
    k_scan_b<<<1, 128, 0, stream>>>(part);
    k_scan_c<<<SCAN_NBLK, 1024, 0, stream>>>(degc, part, rows, curs, degf);
    k_scatter<<<(EE + 255) / 256, 256, 0, stream>>>(srcp, dstp, curs, csrs);
    k_h<<<NN / 16, 256, 0, stream>>>(x, Watt, asrc, adst, hb, xb, ssrc, sdst);
    k_attn<<<NN / 4, 256, 0, stream>>>(hb, ssrc, sdst, rows, degc, csrs, outp);
    k_hop<<<NN / 4, 256, 0, stream>>>(xb, rows, degc, degf, csrs, hop1, (float*)nullptr, 0);
    k_hop<<<NN / 4, 256, 0, stream>>>(hop1, rows, degc, degf, csrs, (unsigned short*)nullptr, hop2, 1);
    k_wcomb<<<65, 64, 0, stream>>>(Wg, bg, Ww, bw, Wc, bc);
    k_final<<<NN / 4, 256, 0, stream>>>(Ww, Wc, bc, hop2, outp);
}

// Round 3
// 511.168 us; speedup vs baseline: 1.1344x; 1.1223x over previous
//
#include <hip/hip_runtime.h>
#include <math.h>

#define NN 100000
#define EE 800000
#define FDIM 64
#define NH 4
#define HO 256            // NH * FDIM
#define NEG 0.2f

#define SCAN_BLK 1024
#define SCAN_NBLK 98      // ceil(100000/1024)

// ---------- workspace layout (bytes) ----------
#define OFF_H      0ull                       // bf16 h: N*256*2 = 51,200,000
#define OFF_HOP1   0ull                       // bf16 hop1 (12.8 MB) aliases h (dead after attn)
#define OFF_HOP2   12800000ull                // fp32 hop2 (25.6 MB), also inside dead h
#define OFF_XB     51200000ull                // bf16 x: 12.8 MB
#define OFF_SSRC   64000000ull                // N*4 fp32
#define OFF_SDST   65600000ull
#define OFF_DEGC   67200000ull                // N int
#define OFF_ROWS   67600000ull
#define OFF_CURS   68000000ull
#define OFF_DEGF   68400000ull
#define OFF_PART   68800000ull
#define OFF_CSRS   68801024ull                // E int
#define OFF_WCOMB  72001024ull
#define OFF_BCOMB  72017408ull
#define OFF_WT     72017664ull                // bf16 Wt[h][o][k]: 32768 B
#define OFF_WAS    72050432ull                // fp32 waS[4][64]
#define OFF_WAD    72051456ull                // fp32 waD[4][64]
#define WS_NEEDED  72052480ull

typedef __attribute__((ext_vector_type(8))) short bf16x8;
typedef __attribute__((ext_vector_type(4))) float f32x4;

__device__ __forceinline__ float bflo(unsigned int u) { return __uint_as_float(u << 16); }
__device__ __forceinline__ float bfhi(unsigned int u) { return __uint_as_float(u & 0xffff0000u); }
__device__ __forceinline__ unsigned short f2bf(float f) {
    unsigned int u = __float_as_uint(f);
    unsigned int r = u + 0x7fffu + ((u >> 16) & 1u);   // RNE
    return (unsigned short)(r >> 16);
}
__device__ __forceinline__ float lrelu(float x) { return x > 0.f ? x : NEG * x; }

// ---------- K0: prep — Wt[h][o][k]=bf16(Watt[h][k][o]); waS/waD folds ----------
__global__ __launch_bounds__(256) void k_prep(
    const float* __restrict__ Watt, const float* __restrict__ asrc,
    const float* __restrict__ adst,
    unsigned short* __restrict__ Wt, float* __restrict__ waS, float* __restrict__ waD)
{
    const int t = threadIdx.x;
    for (int idx = t; idx < 16384; idx += 256) {
        const int h = idx >> 12, o = (idx >> 6) & 63, k = idx & 63;
        Wt[idx] = f2bf(Watt[h * 4096 + k * 64 + o]);
    }
    // waS[h][i] = sum_o Watt[h][i][o]*asrc[h][o]; waD likewise
    const int h = t >> 6, i = t & 63;
    float aS = 0.f, aD = 0.f;
    for (int o = 0; o < 64; o++) {
        const float w = Watt[h * 4096 + i * 64 + o];
        aS += w * asrc[h * 64 + o];
        aD += w * adst[h * 64 + o];
    }
    waS[t] = aS;
    waD[t] = aD;
}

// ---------- K1: MFMA h = x@W per head; ssrc/sdst from waS/waD; emit xb -----------
// block = 256 = 4 waves; 16 nodes per block; wave w computes head w.
__global__ __launch_bounds__(256) void k_h(
    const float* __restrict__ x, const unsigned short* __restrict__ Wt,
    const float* __restrict__ waS, const float* __restrict__ waD,
    unsigned short* __restrict__ hb, unsigned short* __restrict__ xb,
    float* __restrict__ ssrc, float* __restrict__ sdst)
{
    __shared__ float xs[16 * 64];            // fp32 x tile (for scores)
    __shared__ unsigned short xsb[16 * 64];  // bf16 x tile (MFMA A)
    __shared__ unsigned short hs[16 * 256];  // bf16 h tile (C staging)
    __shared__ float wl[2 * 256];            // waS | waD
    const int t = threadIdx.x;
    const int n0 = blockIdx.x * 16;
    {
        const int r = t >> 4, c4 = (t & 15) * 4;
        const float4 v = *(const float4*)&x[(size_t)(n0 + r) * 64 + c4];
        *(float4*)&xs[r * 64 + c4] = v;
        uint2 p;
        p.x = (unsigned int)f2bf(v.x) | ((unsigned int)f2bf(v.y) << 16);
        p.y = (unsigned int)f2bf(v.z) | ((unsigned int)f2bf(v.w) << 16);
        *(uint2*)&xsb[r * 64 + c4] = p;
        wl[t] = waS[t];
        wl[256 + t] = waD[t];
    }
    __syncthreads();
    // emit bf16 x rows for hop gathers (16 rows x 128 B)
    if (t < 128) {
        const int r = t >> 3, c8 = (t & 7) * 8;
        const uint4 v = *(const uint4*)&xsb[r * 64 + c8];
        *(uint4*)&xb[(size_t)(n0 + r) * 64 + c8] = v;
    }
    // scores: thread t -> node nl, head hh, quarter q of the 64-dot
    {
        const int nl = t >> 4, hh = (t >> 2) & 3, q = t & 3;
        const float* xr = &xs[nl * 64 + q * 16];
        const float* wS = &wl[hh * 64 + q * 16];
        const float* wD = &wl[256 + hh * 64 + q * 16];
        float pS = 0.f, pD = 0.f;
#pragma unroll
        for (int i = 0; i < 16; i++) { pS += xr[i] * wS[i]; pD += xr[i] * wD[i]; }
        pS += __shfl_xor(pS, 1); pS += __shfl_xor(pS, 2);
        pD += __shfl_xor(pD, 1); pD += __shfl_xor(pD, 2);
        if (q == 0) {
            ssrc[(n0 + nl) * 4 + hh] = pS;
            sdst[(n0 + nl) * 4 + hh] = pD;
        }
    }
    // MFMA: D[n(16) x o(16)] tiles, K=64 in two x32 steps
    const int w = t >> 6, lane = t & 63;
    const int m = lane & 15, quad = lane >> 4;
    const bf16x8 a0 = *(const bf16x8*)&xsb[m * 64 + quad * 8];        // k 0..31
    const bf16x8 a1 = *(const bf16x8*)&xsb[m * 64 + 32 + quad * 8];   // k 32..63
    f32x4 acc[4] = {{0.f,0.f,0.f,0.f},{0.f,0.f,0.f,0.f},{0.f,0.f,0.f,0.f},{0.f,0.f,0.f,0.f}};
#pragma unroll
    for (int ot = 0; ot < 4; ot++) {
        const unsigned short* wp = Wt + w * 4096 + (ot * 16 + m) * 64 + quad * 8;
        const bf16x8 b0 = *(const bf16x8*)wp;          // k 0..31
        const bf16x8 b1 = *(const bf16x8*)(wp + 32);   // k 32..63
        acc[ot] = __builtin_amdgcn_mfma_f32_16x16x32_bf16(a0, b0, acc[ot], 0, 0, 0);
        acc[ot] = __builtin_amdgcn_mfma_f32_16x16x32_bf16(a1, b1, acc[ot], 0, 0, 0);
    }
    // C/D layout: col=lane&15, row=quad*4+r
#pragma unroll
    for (int ot = 0; ot < 4; ot++)
#pragma unroll
        for (int r = 0; r < 4; r++)
            hs[(quad * 4 + r) * 256 + w * 64 + ot * 16 + m] = f2bf(acc[ot][r]);
    __syncthreads();
    {
        const int r = t >> 4, c0 = (t & 15) * 16;
        const uint4 v0 = *(const uint4*)&hs[r * 256 + c0];
        const uint4 v1 = *(const uint4*)&hs[r * 256 + c0 + 8];
        *(uint4*)&hb[(size_t)(n0 + r) * 256 + c0] = v0;
        *(uint4*)&hb[(size_t)(n0 + r) * 256 + c0 + 8] = v1;
    }
}

// ---------- K2: in-degree histogram ----------
__global__ void k_hist(const int* __restrict__ dst, int* __restrict__ degc) {
    int e = blockIdx.x * 256 + threadIdx.x;
    if (e < EE) atomicAdd(&degc[dst[e]], 1);
}

// ---------- K3: 3-kernel exclusive scan ----------
__global__ __launch_bounds__(1024) void k_scan_a(const int* __restrict__ degc, int* __restrict__ part) {
    __shared__ int sh[1024];
    int t = threadIdx.x;
    int i = blockIdx.x * SCAN_BLK + t;
    sh[t] = (i < NN) ? degc[i] : 0;
    __syncthreads();
    for (int off = 512; off > 0; off >>= 1) {
        if (t < off) sh[t] += sh[t + off];
        __syncthreads();
    }
    if (t == 0) part[blockIdx.x] = sh[0];
}

__global__ __launch_bounds__(128) void k_scan_b(int* part) {
    __shared__ int sh[128];
    int t = threadIdx.x;
    int v = (t < SCAN_NBLK) ? part[t] : 0;
    sh[t] = v;
    __syncthreads();
    for (int off = 1; off < 128; off <<= 1) {
        int tmp = (t >= off) ? sh[t - off] : 0;
        __syncthreads();
        sh[t] += tmp;
        __syncthreads();
    }
    if (t < SCAN_NBLK) part[t] = sh[t] - v;   // exclusive
}

__global__ __launch_bounds__(1024) void k_scan_c(
    const int* __restrict__ degc, const int* __restrict__ part,
    int* __restrict__ rows, int* __restrict__ curs, float* __restrict__ degf)
{
    __shared__ int sh[1024];
    int t = threadIdx.x;
    int i = blockIdx.x * SCAN_BLK + t;
    int v = (i < NN) ? degc[i] : 0;
    sh[t] = v;
    __syncthreads();
    for (int off = 1; off < 1024; off <<= 1) {
        int tmp = (t >= off) ? sh[t - off] : 0;
        __syncthreads();
        sh[t] += tmp;
        __syncthreads();
    }
    int excl = sh[t] - v + part[blockIdx.x];
    if (i < NN) {
        rows[i] = excl;
        curs[i] = excl;
        degf[i] = (float)max(v, 1);
    }
}

// ---------- K4: scatter edges into CSR (by dst) ----------
__global__ void k_scatter(const int* __restrict__ src, const int* __restrict__ dst,
                          int* __restrict__ curs, int* __restrict__ csrs) {
    int e = blockIdx.x * 256 + threadIdx.x;
    if (e < EE) {
        int d = dst[e];
        int pos = atomicAdd(&curs[d], 1);
        csrs[pos] = src[e];
    }
}

// ---------- K5: attention (one wave per dst node, no-max softmax, single pass) ----
__global__ __launch_bounds__(256) void k_attn(
    const unsigned short* __restrict__ hb,
    const float* __restrict__ ssrc, const float* __restrict__ sdst,
    const int* __restrict__ rows, const int* __restrict__ degc,
    const int* __restrict__ csrs, float* __restrict__ local)
{
    const int lane = threadIdx.x & 63;
    const int n = blockIdx.x * 4 + (threadIdx.x >> 6);
    if (n >= NN) return;
    const int start = rows[n], cnt = degc[n];
    const int hh = lane >> 4, c = lane & 15;
    const int permbase = (lane & 48) * 4;
    float4 acc = {0.f, 0.f, 0.f, 0.f};
    if (cnt > 0) {
        const float4 sd = *(const float4*)&sdst[n * 4];
        float den = 0.f;
        for (int base = 0; base < cnt; base += 16) {
            const int j = base + c;
            int sj = 0; float exsel = 0.f;
            if (j < cnt) {
                sj = csrs[start + j];
                const float4 ss = *(const float4*)&ssrc[sj * 4];
                const float e0 = __expf(lrelu(ss.x + sd.x));
                const float e1 = __expf(lrelu(ss.y + sd.y));
                const float e2 = __expf(lrelu(ss.z + sd.z));
                const float e3 = __expf(lrelu(ss.w + sd.w));
                exsel = (hh == 0) ? e0 : (hh == 1) ? e1 : (hh == 2) ? e2 : e3;
            }
            den += exsel;
            const int lim = min(16, cnt - base);
            for (int jj = 0; jj < lim; jj++) {
                const int   s = __shfl(sj,    (permbase >> 2) + jj);
                const float a = __shfl(exsel, (permbase >> 2) + jj);
                const uint2 u = *(const uint2*)&hb[(size_t)s * HO + lane * 4];
                acc.x += a * bflo(u.x);
                acc.y += a * bfhi(u.x);
                acc.z += a * bflo(u.y);
                acc.w += a * bfhi(u.y);
            }
        }
        den += __shfl_xor(den, 1);
        den += __shfl_xor(den, 2);
        den += __shfl_xor(den, 4);
        den += __shfl_xor(den, 8);
        const float inv = 1.f / den;
        acc.x *= inv; acc.y *= inv; acc.z *= inv; acc.w *= inv;
    }
#pragma unroll
    for (int off = 16; off < 64; off <<= 1) {
        acc.x += __shfl_xor(acc.x, off);
        acc.y += __shfl_xor(acc.y, off);
        acc.z += __shfl_xor(acc.z, off);
        acc.w += __shfl_xor(acc.w, off);
    }
    if (lane < 16) {
        float4 o = {acc.x * 0.25f, acc.y * 0.25f, acc.z * 0.25f, acc.w * 0.25f};
        *(float4*)&local[(size_t)n * 64 + lane * 4] = o;
    }
}

// ---------- K6/K7: one mean-aggregation hop, bf16 gather (wave per node) --------
__global__ __launch_bounds__(256) void k_hop(
    const unsigned short* __restrict__ xin, const int* __restrict__ rows,
    const int* __restrict__ degc, const float* __restrict__ degf,
    const int* __restrict__ csrs,
    unsigned short* __restrict__ out_b, float* __restrict__ out_f, int out_fp32)
{
    const int lane = threadIdx.x & 63;
    const int n = blockIdx.x * 4 + (threadIdx.x >> 6);
    if (n >= NN) return;
    const int start = rows[n], cnt = degc[n];
    const int half = lane >> 5, c = lane & 31;
    float a0 = 0.f, a1 = 0.f;
    for (int j = half; j < cnt; j += 2) {
        const int s = csrs[start + j];
        const unsigned int u = *(const unsigned int*)&xin[(size_t)s * 64 + c * 2];
        a0 += bflo(u);
        a1 += bfhi(u);
    }
    a0 += __shfl_xor(a0, 32);
    a1 += __shfl_xor(a1, 32);
    if (lane < 32) {
        const float inv = 1.f / degf[n];
        a0 *= inv; a1 *= inv;
        if (out_fp32) {
            float2 o = {a0, a1};
            *(float2*)&out_f[(size_t)n * 64 + c * 2] = o;
        } else {
            unsigned int p = (unsigned int)f2bf(a0) | ((unsigned int)f2bf(a1) << 16);
            *(unsigned int*)&out_b[(size_t)n * 64 + c * 2] = p;
        }
    }
}

// ---------- K8: fold W_g / b_g through W_w bottom half ----------
__global__ __launch_bounds__(64) void k_wcomb(
    const float* __restrict__ Wg, const float* __restrict__ bg,
    const float* __restrict__ Ww, const float* __restrict__ bw,
    float* __restrict__ Wc, float* __restrict__ bc)
{
    int c = threadIdx.x;
    int b = blockIdx.x;
    if (b < 64) {
        float a = 0.f;
        for (int m = 0; m < 64; m++) a += Wg[b * 64 + m] * Ww[(64 + m) * 64 + c];
        Wc[b * 64 + c] = a;
    } else {
        float a = bw[c];
        for (int m = 0; m < 64; m++) a += bg[m] * Ww[(64 + m) * 64 + c];
        bc[c] = a;
    }
}

// ---------- K9: out = local @ Ww_top + hop2 @ Wc + bc  (in-place on d_out) ----------
__global__ __launch_bounds__(256) void k_final(
    const float* __restrict__ Ww, const float* __restrict__ Wc,
    const float* __restrict__ bc, const float* __restrict__ hop2,
    float* __restrict__ outp)
{
    __shared__ float W1s[64 * 64];
    __shared__ float Wcs[64 * 64];
    __shared__ float lr[4 * 64];
    __shared__ float gr[4 * 64];
    const int t = threadIdx.x;
    const int n0 = blockIdx.x * 4;
#pragma unroll
    for (int k = 0; k < 16; k++) {
        W1s[t + k * 256] = Ww[t + k * 256];
        Wcs[t + k * 256] = Wc[t + k * 256];
    }
    lr[t] = outp[(size_t)n0 * 64 + t];
    gr[t] = hop2[(size_t)n0 * 64 + t];
    __syncthreads();
    const int nl = t >> 6, c = t & 63;
    float a = bc[c];
    for (int k = 0; k < 64; k += 4) {
        a += lr[nl * 64 + k + 0] * W1s[(k + 0) * 64 + c] + gr[nl * 64 + k + 0] * Wcs[(k + 0) * 64 + c];
        a += lr[nl * 64 + k + 1] * W1s[(k + 1) * 64 + c] + gr[nl * 64 + k + 1] * Wcs[(k + 1) * 64 + c];
        a += lr[nl * 64 + k + 2] * W1s[(k + 2) * 64 + c] + gr[nl * 64 + k + 2] * Wcs[(k + 2) * 64 + c];
        a += lr[nl * 64 + k + 3] * W1s[(k + 3) * 64 + c] + gr[nl * 64 + k + 3] * Wcs[(k + 3) * 64 + c];
    }
    outp[(size_t)(n0 + nl) * 64 + c] = a;
}

extern "C" void kernel_launch(void* const* d_in, const int* in_sizes, int n_in,
                              void* d_out, int out_size, void* d_ws, size_t ws_size,
                              hipStream_t stream)
{
    const float* x    = (const float*)d_in[0];
    const int*   ei   = (const int*)d_in[1];
    const int*   srcp = ei;
    const int*   dstp = ei + EE;
    const float* Watt = (const float*)d_in[2];
    const float* asrc = (const float*)d_in[3];
    const float* adst = (const float*)d_in[4];
    const float* Wg   = (const float*)d_in[5];
    const float* bg   = (const float*)d_in[6];
    const float* Ww   = (const float*)d_in[7];
    const float* bw   = (const float*)d_in[8];
    float* outp = (float*)d_out;

    if (ws_size < WS_NEEDED) return;   // fail loudly (validation will catch)

    char* ws = (char*)d_ws;
    unsigned short* hb   = (unsigned short*)(ws + OFF_H);
    unsigned short* hop1 = (unsigned short*)(ws + OFF_HOP1);  // aliases hb (dead)
    float*          hop2 = (float*)(ws + OFF_HOP2);           // inside dead hb too
    unsigned short* xb   = (unsigned short*)(ws + OFF_XB);
    float* ssrc = (float*)(ws + OFF_SSRC);
    float* sdst = (float*)(ws + OFF_SDST);
    int*   degc = (int*)(ws + OFF_DEGC);
    int*   rows = (int*)(ws + OFF_ROWS);
    int*   curs = (int*)(ws + OFF_CURS);
    float* degf = (float*)(ws + OFF_DEGF);
    int*   part = (int*)(ws + OFF_PART);
    int*   csrs = (int*)(ws + OFF_CSRS);
    float* Wc   = (float*)(ws + OFF_WCOMB);
    float* bc   = (float*)(ws + OFF_BCOMB);
    unsigned short* Wt = (unsigned short*)(ws + OFF_WT);
    float* waS  = (float*)(ws + OFF_WAS);
    float* waD  = (float*)(ws + OFF_WAD);

    hipMemsetAsync(degc, 0, NN * sizeof(int), stream);
    k_prep<<<1, 256, 0, stream>>>(Watt, asrc, adst, Wt, waS, waD);
    k_hist<<<(EE + 255) / 256, 256, 0, stream>>>(dstp, degc);
    k_scan_a<<<SCAN_NBLK, 1024, 0, stream>>>(degc, part);
    k_scan_b<<<1, 128, 0, stream>>>(part);
    k_scan_c<<<SCAN_NBLK, 1024, 0, stream>>>(degc, part, rows, curs, degf);
    k_scatter<<<(EE + 255) / 256, 256, 0, stream>>>(srcp, dstp, curs, csrs);
    k_h<<<NN / 16, 256, 0, stream>>>(x, Wt, waS, waD, hb, xb, ssrc, sdst);
    k_attn<<<NN / 4, 256, 0, stream>>>(hb, ssrc, sdst, rows, degc, csrs, outp);
    k_hop<<<NN / 4, 256, 0, stream>>>(xb, rows, degc, degf, csrs, hop1, (float*)nullptr, 0);
    k_hop<<<NN / 4, 256, 0, stream>>>(hop1, rows, degc, degf, csrs, (unsigned short*)nullptr, hop2, 1);
    k_wcomb<<<65, 64, 0, stream>>>(Wg, bg, Ww, bw, Wc, bc);
    k_final<<<NN / 4, 256, 0, stream>>>(Ww, Wc, bc, hop2, outp);
}

// Round 4
// 460.471 us; speedup vs baseline: 1.2592x; 1.1101x over previous
//
#include <hip/hip_runtime.h>
#include <math.h>

#define NN 100000
#define EE 800000
#define FDIM 64
#define NH 4
#define HO 256            // NH * FDIM
#define NEG 0.2f

#define SCAN_BLK 1024
#define SCAN_NBLK 98      // ceil(100000/1024)

// ---------- workspace layout (bytes) ----------
#define OFF_H      0ull                       // bf16 h: N*256*2 = 51,200,000
#define OFF_HOP1   0ull                       // bf16 hop1 (12.8 MB) aliases h (dead after attn)
#define OFF_HOP2   12800000ull                // bf16 hop2 (12.8 MB), inside dead h
#define OFF_XB     51200000ull                // bf16 x: 12.8 MB
#define OFF_SSRC   64000000ull                // N*4 fp32
#define OFF_SDST   65600000ull
#define OFF_DEGC   67200000ull                // N int
#define OFF_ROWS   67600000ull
#define OFF_CURS   68000000ull
#define OFF_DEGF   68400000ull
#define OFF_PART   68800000ull
#define OFF_CSRS   68801024ull                // E int
#define OFF_WCAT   72001024ull                // bf16 Wcat[64][128] = 16384 B
#define OFF_BCOMB  72017408ull                // fp32 bc[64]
#define OFF_WT     72017664ull                // bf16 Wt[h][o][k]: 32768 B
#define OFF_WAS    72050432ull                // fp32 waS[4][64]
#define OFF_WAD    72051456ull                // fp32 waD[4][64]
#define WS_NEEDED  72052480ull

typedef __attribute__((ext_vector_type(8))) short bf16x8;
typedef __attribute__((ext_vector_type(4))) float f32x4;

__device__ __forceinline__ float bflo(unsigned int u) { return __uint_as_float(u << 16); }
__device__ __forceinline__ float bfhi(unsigned int u) { return __uint_as_float(u & 0xffff0000u); }
__device__ __forceinline__ unsigned short f2bf(float f) {
    unsigned int u = __float_as_uint(f);
    unsigned int r = u + 0x7fffu + ((u >> 16) & 1u);   // RNE
    return (unsigned short)(r >> 16);
}
__device__ __forceinline__ float lrelu(float x) { return x > 0.f ? x : NEG * x; }

// ---------- K0: prep — Wt[h][o][k]=bf16(Watt[h][k][o]); waS/waD folds ----------
__global__ __launch_bounds__(256) void k_prep(
    const float* __restrict__ Watt, const float* __restrict__ asrc,
    const float* __restrict__ adst,
    unsigned short* __restrict__ Wt, float* __restrict__ waS, float* __restrict__ waD)
{
    const int t = threadIdx.x;
    for (int idx = t; idx < 16384; idx += 256) {
        const int h = idx >> 12, o = (idx >> 6) & 63, k = idx & 63;
        Wt[idx] = f2bf(Watt[h * 4096 + k * 64 + o]);
    }
    const int h = t >> 6, i = t & 63;
    float aS = 0.f, aD = 0.f;
    for (int o = 0; o < 64; o++) {
        const float w = Watt[h * 4096 + i * 64 + o];
        aS += w * asrc[h * 64 + o];
        aD += w * adst[h * 64 + o];
    }
    waS[t] = aS;
    waD[t] = aD;
}

// ---------- K1: MFMA h = x@W per head; ssrc/sdst from waS/waD; emit xb -----------
__global__ __launch_bounds__(256) void k_h(
    const float* __restrict__ x, const unsigned short* __restrict__ Wt,
    const float* __restrict__ waS, const float* __restrict__ waD,
    unsigned short* __restrict__ hb, unsigned short* __restrict__ xb,
    float* __restrict__ ssrc, float* __restrict__ sdst)
{
    __shared__ float xs[16 * 64];
    __shared__ unsigned short xsb[16 * 64];
    __shared__ unsigned short hs[16 * 256];
    __shared__ float wl[2 * 256];
    const int t = threadIdx.x;
    const int n0 = blockIdx.x * 16;
    {
        const int r = t >> 4, c4 = (t & 15) * 4;
        const float4 v = *(const float4*)&x[(size_t)(n0 + r) * 64 + c4];
        *(float4*)&xs[r * 64 + c4] = v;
        uint2 p;
        p.x = (unsigned int)f2bf(v.x) | ((unsigned int)f2bf(v.y) << 16);
        p.y = (unsigned int)f2bf(v.z) | ((unsigned int)f2bf(v.w) << 16);
        *(uint2*)&xsb[r * 64 + c4] = p;
        wl[t] = waS[t];
        wl[256 + t] = waD[t];
    }
    __syncthreads();
    if (t < 128) {
        const int r = t >> 3, c8 = (t & 7) * 8;
        const uint4 v = *(const uint4*)&xsb[r * 64 + c8];
        *(uint4*)&xb[(size_t)(n0 + r) * 64 + c8] = v;
    }
    {
        const int nl = t >> 4, hh = (t >> 2) & 3, q = t & 3;
        const float* xr = &xs[nl * 64 + q * 16];
        const float* wS = &wl[hh * 64 + q * 16];
        const float* wD = &wl[256 + hh * 64 + q * 16];
        float pS = 0.f, pD = 0.f;
#pragma unroll
        for (int i = 0; i < 16; i++) { pS += xr[i] * wS[i]; pD += xr[i] * wD[i]; }
        pS += __shfl_xor(pS, 1); pS += __shfl_xor(pS, 2);
        pD += __shfl_xor(pD, 1); pD += __shfl_xor(pD, 2);
        if (q == 0) {
            ssrc[(n0 + nl) * 4 + hh] = pS;
            sdst[(n0 + nl) * 4 + hh] = pD;
        }
    }
    const int w = t >> 6, lane = t & 63;
    const int m = lane & 15, quad = lane >> 4;
    const bf16x8 a0 = *(const bf16x8*)&xsb[m * 64 + quad * 8];
    const bf16x8 a1 = *(const bf16x8*)&xsb[m * 64 + 32 + quad * 8];
    f32x4 acc[4] = {{0.f,0.f,0.f,0.f},{0.f,0.f,0.f,0.f},{0.f,0.f,0.f,0.f},{0.f,0.f,0.f,0.f}};
#pragma unroll
    for (int ot = 0; ot < 4; ot++) {
        const unsigned short* wp = Wt + w * 4096 + (ot * 16 + m) * 64 + quad * 8;
        const bf16x8 b0 = *(const bf16x8*)wp;
        const bf16x8 b1 = *(const bf16x8*)(wp + 32);
        acc[ot] = __builtin_amdgcn_mfma_f32_16x16x32_bf16(a0, b0, acc[ot], 0, 0, 0);
        acc[ot] = __builtin_amdgcn_mfma_f32_16x16x32_bf16(a1, b1, acc[ot], 0, 0, 0);
    }
#pragma unroll
    for (int ot = 0; ot < 4; ot++)
#pragma unroll
        for (int r = 0; r < 4; r++)
            hs[(quad * 4 + r) * 256 + w * 64 + ot * 16 + m] = f2bf(acc[ot][r]);
    __syncthreads();
    {
        const int r = t >> 4, c0 = (t & 15) * 16;
        const uint4 v0 = *(const uint4*)&hs[r * 256 + c0];
        const uint4 v1 = *(const uint4*)&hs[r * 256 + c0 + 8];
        *(uint4*)&hb[(size_t)(n0 + r) * 256 + c0] = v0;
        *(uint4*)&hb[(size_t)(n0 + r) * 256 + c0 + 8] = v1;
    }
}

// ---------- K2: in-degree histogram ----------
__global__ void k_hist(const int* __restrict__ dst, int* __restrict__ degc) {
    int e = blockIdx.x * 256 + threadIdx.x;
    if (e < EE) atomicAdd(&degc[dst[e]], 1);
}

// ---------- K3: 3-kernel exclusive scan ----------
__global__ __launch_bounds__(1024) void k_scan_a(const int* __restrict__ degc, int* __restrict__ part) {
    __shared__ int sh[1024];
    int t = threadIdx.x;
    int i = blockIdx.x * SCAN_BLK + t;
    sh[t] = (i < NN) ? degc[i] : 0;
    __syncthreads();
    for (int off = 512; off > 0; off >>= 1) {
        if (t < off) sh[t] += sh[t + off];
        __syncthreads();
    }
    if (t == 0) part[blockIdx.x] = sh[0];
}

__global__ __launch_bounds__(128) void k_scan_b(int* part) {
    __shared__ int sh[128];
    int t = threadIdx.x;
    int v = (t < SCAN_NBLK) ? part[t] : 0;
    sh[t] = v;
    __syncthreads();
    for (int off = 1; off < 128; off <<= 1) {
        int tmp = (t >= off) ? sh[t - off] : 0;
        __syncthreads();
        sh[t] += tmp;
        __syncthreads();
    }
    if (t < SCAN_NBLK) part[t] = sh[t] - v;   // exclusive
}

__global__ __launch_bounds__(1024) void k_scan_c(
    const int* __restrict__ degc, const int* __restrict__ part,
    int* __restrict__ rows, int* __restrict__ curs, float* __restrict__ degf)
{
    __shared__ int sh[1024];
    int t = threadIdx.x;
    int i = blockIdx.x * SCAN_BLK + t;
    int v = (i < NN) ? degc[i] : 0;
    sh[t] = v;
    __syncthreads();
    for (int off = 1; off < 1024; off <<= 1) {
        int tmp = (t >= off) ? sh[t - off] : 0;
        __syncthreads();
        sh[t] += tmp;
        __syncthreads();
    }
    int excl = sh[t] - v + part[blockIdx.x];
    if (i < NN) {
        rows[i] = excl;
        curs[i] = excl;
        degf[i] = (float)max(v, 1);
    }
}

// ---------- K4: scatter edges into CSR (by dst) ----------
__global__ void k_scatter(const int* __restrict__ src, const int* __restrict__ dst,
                          int* __restrict__ curs, int* __restrict__ csrs) {
    int e = blockIdx.x * 256 + threadIdx.x;
    if (e < EE) {
        int d = dst[e];
        int pos = atomicAdd(&curs[d], 1);
        csrs[pos] = src[e];
    }
}

// ---------- K5: attention; writes bf16 local into first 128B of each 256B d_out slot
__global__ __launch_bounds__(256) void k_attn(
    const unsigned short* __restrict__ hb,
    const float* __restrict__ ssrc, const float* __restrict__ sdst,
    const int* __restrict__ rows, const int* __restrict__ degc,
    const int* __restrict__ csrs, char* __restrict__ outb)
{
    const int lane = threadIdx.x & 63;
    const int n = blockIdx.x * 4 + (threadIdx.x >> 6);
    if (n >= NN) return;
    const int start = rows[n], cnt = degc[n];
    const int hh = lane >> 4, c = lane & 15;
    const int permbase = (lane & 48) * 4;
    float4 acc = {0.f, 0.f, 0.f, 0.f};
    if (cnt > 0) {
        const float4 sd = *(const float4*)&sdst[n * 4];
        float den = 0.f;
        for (int base = 0; base < cnt; base += 16) {
            const int j = base + c;
            int sj = 0; float exsel = 0.f;
            if (j < cnt) {
                sj = csrs[start + j];
                const float4 ss = *(const float4*)&ssrc[sj * 4];
                const float e0 = __expf(lrelu(ss.x + sd.x));
                const float e1 = __expf(lrelu(ss.y + sd.y));
                const float e2 = __expf(lrelu(ss.z + sd.z));
                const float e3 = __expf(lrelu(ss.w + sd.w));
                exsel = (hh == 0) ? e0 : (hh == 1) ? e1 : (hh == 2) ? e2 : e3;
            }
            den += exsel;
            const int lim = min(16, cnt - base);
            for (int jj = 0; jj < lim; jj++) {
                const int   s = __shfl(sj,    (permbase >> 2) + jj);
                const float a = __shfl(exsel, (permbase >> 2) + jj);
                const uint2 u = *(const uint2*)&hb[(size_t)s * HO + lane * 4];
                acc.x += a * bflo(u.x);
                acc.y += a * bfhi(u.x);
                acc.z += a * bflo(u.y);
                acc.w += a * bfhi(u.y);
            }
        }
        den += __shfl_xor(den, 1);
        den += __shfl_xor(den, 2);
        den += __shfl_xor(den, 4);
        den += __shfl_xor(den, 8);
        const float inv = 1.f / den;
        acc.x *= inv; acc.y *= inv; acc.z *= inv; acc.w *= inv;
    }
#pragma unroll
    for (int off = 16; off < 64; off <<= 1) {
        acc.x += __shfl_xor(acc.x, off);
        acc.y += __shfl_xor(acc.y, off);
        acc.z += __shfl_xor(acc.z, off);
        acc.w += __shfl_xor(acc.w, off);
    }
    if (lane < 16) {
        uint2 p;
        p.x = (unsigned int)f2bf(acc.x * 0.25f) | ((unsigned int)f2bf(acc.y * 0.25f) << 16);
        p.y = (unsigned int)f2bf(acc.z * 0.25f) | ((unsigned int)f2bf(acc.w * 0.25f) << 16);
        *(uint2*)(outb + (size_t)n * 256 + lane * 8) = p;
    }
}

// ---------- K6/K7: one mean-aggregation hop, bf16 gather (wave per node) --------
__global__ __launch_bounds__(256) void k_hop(
    const unsigned short* __restrict__ xin, const int* __restrict__ rows,
    const int* __restrict__ degc, const float* __restrict__ degf,
    const int* __restrict__ csrs,
    unsigned short* __restrict__ out_b, float* __restrict__ out_f, int out_fp32)
{
    const int lane = threadIdx.x & 63;
    const int n = blockIdx.x * 4 + (threadIdx.x >> 6);
    if (n >= NN) return;
    const int start = rows[n], cnt = degc[n];
    const int half = lane >> 5, c = lane & 31;
    float a0 = 0.f, a1 = 0.f;
    for (int j = half; j < cnt; j += 2) {
        const int s = csrs[start + j];
        const unsigned int u = *(const unsigned int*)&xin[(size_t)s * 64 + c * 2];
        a0 += bflo(u);
        a1 += bfhi(u);
    }
    a0 += __shfl_xor(a0, 32);
    a1 += __shfl_xor(a1, 32);
    if (lane < 32) {
        const float inv = 1.f / degf[n];
        a0 *= inv; a1 *= inv;
        if (out_fp32) {
            float2 o = {a0, a1};
            *(float2*)&out_f[(size_t)n * 64 + c * 2] = o;
        } else {
            unsigned int p = (unsigned int)f2bf(a0) | ((unsigned int)f2bf(a1) << 16);
            *(unsigned int*)&out_b[(size_t)n * 64 + c * 2] = p;
        }
    }
}

// ---------- K8: build bf16 Wcat[c][k] = [Ww_top ; Wg@Ww_bot]^T, bc ----------
__global__ __launch_bounds__(1024) void k_wcomb(
    const float* __restrict__ Wg, const float* __restrict__ bg,
    const float* __restrict__ Ww, const float* __restrict__ bw,
    unsigned short* __restrict__ Wcat, float* __restrict__ bc)
{
    __shared__ float WcF[64 * 64];
    const int t = threadIdx.x;
    for (int idx = t; idx < 4096; idx += 1024) {
        const int b = idx >> 6, c = idx & 63;
        float a = 0.f;
        for (int m = 0; m < 64; m++) a += Wg[b * 64 + m] * Ww[(64 + m) * 64 + c];
        WcF[idx] = a;
    }
    if (t < 64) {
        float a = bw[t];
        for (int m = 0; m < 64; m++) a += bg[m] * Ww[(64 + m) * 64 + t];
        bc[t] = a;
    }
    __syncthreads();
    for (int idx = t; idx < 8192; idx += 1024) {
        const int c = idx >> 7, k = idx & 127;
        const float v = (k < 64) ? Ww[k * 64 + c] : WcF[(k - 64) * 64 + c];
        Wcat[idx] = f2bf(v);
    }
}

// ---------- K9: MFMA out = cat(localb,hop2b) @ Wcat + bc; 64 nodes/block -------
__global__ __launch_bounds__(256) void k_final(
    const unsigned short* __restrict__ Wcat, const float* __restrict__ bc,
    const unsigned short* __restrict__ hop2b, float* __restrict__ outp)
{
    __shared__ float os[64 * 68];   // stride 68 words: 2-way-max bank aliasing
    __shared__ float bcl[64];
    const int t = threadIdx.x;
    const int n0 = blockIdx.x * 64;
    if (t < 64) bcl[t] = bc[t];
    const int w = t >> 6, lane = t & 63, m = lane & 15, quad = lane >> 4;
    const int node = n0 + w * 16 + m;
    const int nld = min(node, NN - 1);
    const unsigned short* lrow = (const unsigned short*)((const char*)outp + (size_t)nld * 256);
    const unsigned short* grow = &hop2b[(size_t)nld * 64];
    const bf16x8 a0 = *(const bf16x8*)&lrow[quad * 8];
    const bf16x8 a1 = *(const bf16x8*)&lrow[32 + quad * 8];
    const bf16x8 a2 = *(const bf16x8*)&grow[quad * 8];
    const bf16x8 a3 = *(const bf16x8*)&grow[32 + quad * 8];
    f32x4 acc[4] = {{0.f,0.f,0.f,0.f},{0.f,0.f,0.f,0.f},{0.f,0.f,0.f,0.f},{0.f,0.f,0.f,0.f}};
#pragma unroll
    for (int ot = 0; ot < 4; ot++) {
        const unsigned short* wp = Wcat + (ot * 16 + m) * 128 + quad * 8;
        const bf16x8 b0 = *(const bf16x8*)wp;
        const bf16x8 b1 = *(const bf16x8*)(wp + 32);
        const bf16x8 b2 = *(const bf16x8*)(wp + 64);
        const bf16x8 b3 = *(const bf16x8*)(wp + 96);
        acc[ot] = __builtin_amdgcn_mfma_f32_16x16x32_bf16(a0, b0, acc[ot], 0, 0, 0);
        acc[ot] = __builtin_amdgcn_mfma_f32_16x16x32_bf16(a1, b1, acc[ot], 0, 0, 0);
        acc[ot] = __builtin_amdgcn_mfma_f32_16x16x32_bf16(a2, b2, acc[ot], 0, 0, 0);
        acc[ot] = __builtin_amdgcn_mfma_f32_16x16x32_bf16(a3, b3, acc[ot], 0, 0, 0);
    }
    __syncthreads();   // bcl ready; also orders global a-loads before the stores below
#pragma unroll
    for (int ot = 0; ot < 4; ot++)
#pragma unroll
        for (int r = 0; r < 4; r++)
            os[(w * 16 + quad * 4 + r) * 68 + ot * 16 + m] = acc[ot][r] + bcl[ot * 16 + m];
    __syncthreads();
#pragma unroll
    for (int p = 0; p < 4; p++) {
        const int idx = p * 256 + t;
        const int row = idx >> 4, f4 = idx & 15;
        if (n0 + row < NN)
            *(float4*)&outp[(size_t)(n0 + row) * 64 + f4 * 4] = *(const float4*)&os[row * 68 + f4 * 4];
    }
}

extern "C" void kernel_launch(void* const* d_in, const int* in_sizes, int n_in,
                              void* d_out, int out_size, void* d_ws, size_t ws_size,
                              hipStream_t stream)
{
    const float* x    = (const float*)d_in[0];
    const int*   ei   = (const int*)d_in[1];
    const int*   srcp = ei;
    const int*   dstp = ei + EE;
    const float* Watt = (const float*)d_in[2];
    const float* asrc = (const float*)d_in[3];
    const float* adst = (const float*)d_in[4];
    const float* Wg   = (const float*)d_in[5];
    const float* bg   = (const float*)d_in[6];
    const float* Ww   = (const float*)d_in[7];
    const float* bw   = (const float*)d_in[8];
    float* outp = (float*)d_out;

    if (ws_size < WS_NEEDED) return;   // fail loudly (validation will catch)

    char* ws = (char*)d_ws;
    unsigned short* hb    = (unsigned short*)(ws + OFF_H);
    unsigned short* hop1  = (unsigned short*)(ws + OFF_HOP1);  // aliases hb (dead)
    unsigned short* hop2b = (unsigned short*)(ws + OFF_HOP2);  // inside dead hb
    unsigned short* xb    = (unsigned short*)(ws + OFF_XB);
    float* ssrc = (float*)(ws + OFF_SSRC);
    float* sdst = (float*)(ws + OFF_SDST);
    int*   degc = (int*)(ws + OFF_DEGC);
    int*   rows = (int*)(ws + OFF_ROWS);
    int*   curs = (int*)(ws + OFF_CURS);
    float* degf = (float*)(ws + OFF_DEGF);
    int*   part = (int*)(ws + OFF_PART);
    int*   csrs = (int*)(ws + OFF_CSRS);
    unsigned short* Wcat = (unsigned short*)(ws + OFF_WCAT);
    float* bc   = (float*)(ws + OFF_BCOMB);
    unsigned short* Wt = (unsigned short*)(ws + OFF_WT);
    float* waS  = (float*)(ws + OFF_WAS);
    float* waD  = (float*)(ws + OFF_WAD);

    hipMemsetAsync(degc, 0, NN * sizeof(int), stream);
    k_prep<<<1, 256, 0, stream>>>(Watt, asrc, adst, Wt, waS, waD);
    k_hist<<<(EE + 255) / 256, 256, 0, stream>>>(dstp, degc);
    k_scan_a<<<SCAN_NBLK, 1024, 0, stream>>>(degc, part);
    k_scan_b<<<1, 128, 0, stream>>>(part);
    k_scan_c<<<SCAN_NBLK, 1024, 0, stream>>>(degc, part, rows, curs, degf);
    k_scatter<<<(EE + 255) / 256, 256, 0, stream>>>(srcp, dstp, curs, csrs);
    k_h<<<NN / 16, 256, 0, stream>>>(x, Wt, waS, waD, hb, xb, ssrc, sdst);
    k_attn<<<NN / 4, 256, 0, stream>>>(hb, ssrc, sdst, rows, degc, csrs, (char*)d_out);
    k_hop<<<NN / 4, 256, 0, stream>>>(xb, rows, degc, degf, csrs, hop1, (float*)nullptr, 0);
    k_hop<<<NN / 4, 256, 0, stream>>>(hop1, rows, degc, degf, csrs, hop2b, (float*)nullptr, 0);
    k_wcomb<<<1, 1024, 0, stream>>>(Wg, bg, Ww, bw, Wcat, bc);
    k_final<<<(NN + 63) / 64, 256, 0, stream>>>(Wcat, bc, hop2b, outp);
}

// Round 5
// 419.750 us; speedup vs baseline: 1.3814x; 1.0970x over previous
//
#include <hip/hip_runtime.h>
#include <math.h>

#define NN 100000
#define EE 800000
#define FDIM 64
#define NH 4
#define HO 256            // NH * FDIM
#define NEG 0.2f

#define SCAN_BLK 1024
#define SCAN_NBLK 98      // ceil(100000/1024)

// ---------- workspace layout (bytes) ----------
#define OFF_H      0ull                       // bf16 h: N*256*2 = 51,200,000
#define OFF_HOP1   0ull                       // bf16 hop1 (12.8 MB) aliases h (dead after attn)
#define OFF_HOP2   12800000ull                // bf16 hop2 (12.8 MB), inside dead h
#define OFF_XB     51200000ull                // bf16 x: 12.8 MB
#define OFF_SSRC   64000000ull                // N*4 fp32
#define OFF_SDST   65600000ull
#define OFF_DEGC   67200000ull                // N int
#define OFF_ROWS   67600000ull
#define OFF_CURS   68000000ull
#define OFF_DEGF   68400000ull
#define OFF_PART   68800000ull
#define OFF_CSRS   68801024ull                // E int
#define OFF_WCAT   72001024ull                // bf16 Wcat[64][128] = 16384 B
#define OFF_BCOMB  72017408ull                // fp32 bc[64]
#define OFF_WT     72017664ull                // bf16 Wt[h][o][k]: 32768 B
#define OFF_WAS    72050432ull                // fp32 waS[4][64]
#define OFF_WAD    72051456ull                // fp32 waD[4][64]
#define WS_NEEDED  72052480ull

typedef __attribute__((ext_vector_type(8))) short bf16x8;
typedef __attribute__((ext_vector_type(4))) float f32x4;

__device__ __forceinline__ float bflo(unsigned int u) { return __uint_as_float(u << 16); }
__device__ __forceinline__ float bfhi(unsigned int u) { return __uint_as_float(u & 0xffff0000u); }
__device__ __forceinline__ unsigned short f2bf(float f) {
    unsigned int u = __float_as_uint(f);
    unsigned int r = u + 0x7fffu + ((u >> 16) & 1u);   // RNE
    return (unsigned short)(r >> 16);
}
__device__ __forceinline__ float lrelu(float x) { return x > 0.f ? x : NEG * x; }

// ---------- K0: prep — Wt[h][o][k]=bf16(Watt[h][k][o]); waS/waD folds ----------
__global__ __launch_bounds__(256) void k_prep(
    const float* __restrict__ Watt, const float* __restrict__ asrc,
    const float* __restrict__ adst,
    unsigned short* __restrict__ Wt, float* __restrict__ waS, float* __restrict__ waD)
{
    const int t = threadIdx.x;
    for (int idx = t; idx < 16384; idx += 256) {
        const int h = idx >> 12, o = (idx >> 6) & 63, k = idx & 63;
        Wt[idx] = f2bf(Watt[h * 4096 + k * 64 + o]);
    }
    const int h = t >> 6, i = t & 63;
    float aS = 0.f, aD = 0.f;
    for (int o = 0; o < 64; o++) {
        const float w = Watt[h * 4096 + i * 64 + o];
        aS += w * asrc[h * 64 + o];
        aD += w * adst[h * 64 + o];
    }
    waS[t] = aS;
    waD[t] = aD;
}

// ---------- K1: MFMA h = x@W per head; ssrc/sdst from waS/waD; emit xb -----------
__global__ __launch_bounds__(256) void k_h(
    const float* __restrict__ x, const unsigned short* __restrict__ Wt,
    const float* __restrict__ waS, const float* __restrict__ waD,
    unsigned short* __restrict__ hb, unsigned short* __restrict__ xb,
    float* __restrict__ ssrc, float* __restrict__ sdst)
{
    __shared__ float xs[16 * 64];
    __shared__ unsigned short xsb[16 * 64];
    __shared__ unsigned short hs[16 * 256];
    __shared__ float wl[2 * 256];
    const int t = threadIdx.x;
    const int n0 = blockIdx.x * 16;
    {
        const int r = t >> 4, c4 = (t & 15) * 4;
        const float4 v = *(const float4*)&x[(size_t)(n0 + r) * 64 + c4];
        *(float4*)&xs[r * 64 + c4] = v;
        uint2 p;
        p.x = (unsigned int)f2bf(v.x) | ((unsigned int)f2bf(v.y) << 16);
        p.y = (unsigned int)f2bf(v.z) | ((unsigned int)f2bf(v.w) << 16);
        *(uint2*)&xsb[r * 64 + c4] = p;
        wl[t] = waS[t];
        wl[256 + t] = waD[t];
    }
    __syncthreads();
    if (t < 128) {
        const int r = t >> 3, c8 = (t & 7) * 8;
        const uint4 v = *(const uint4*)&xsb[r * 64 + c8];
        *(uint4*)&xb[(size_t)(n0 + r) * 64 + c8] = v;
    }
    {
        const int nl = t >> 4, hh = (t >> 2) & 3, q = t & 3;
        const float* xr = &xs[nl * 64 + q * 16];
        const float* wS = &wl[hh * 64 + q * 16];
        const float* wD = &wl[256 + hh * 64 + q * 16];
        float pS = 0.f, pD = 0.f;
#pragma unroll
        for (int i = 0; i < 16; i++) { pS += xr[i] * wS[i]; pD += xr[i] * wD[i]; }
        pS += __shfl_xor(pS, 1); pS += __shfl_xor(pS, 2);
        pD += __shfl_xor(pD, 1); pD += __shfl_xor(pD, 2);
        if (q == 0) {
            ssrc[(n0 + nl) * 4 + hh] = pS;
            sdst[(n0 + nl) * 4 + hh] = pD;
        }
    }
    const int w = t >> 6, lane = t & 63;
    const int m = lane & 15, quad = lane >> 4;
    const bf16x8 a0 = *(const bf16x8*)&xsb[m * 64 + quad * 8];
    const bf16x8 a1 = *(const bf16x8*)&xsb[m * 64 + 32 + quad * 8];
    f32x4 acc[4] = {{0.f,0.f,0.f,0.f},{0.f,0.f,0.f,0.f},{0.f,0.f,0.f,0.f},{0.f,0.f,0.f,0.f}};
#pragma unroll
    for (int ot = 0; ot < 4; ot++) {
        const unsigned short* wp = Wt + w * 4096 + (ot * 16 + m) * 64 + quad * 8;
        const bf16x8 b0 = *(const bf16x8*)wp;
        const bf16x8 b1 = *(const bf16x8*)(wp + 32);
        acc[ot] = __builtin_amdgcn_mfma_f32_16x16x32_bf16(a0, b0, acc[ot], 0, 0, 0);
        acc[ot] = __builtin_amdgcn_mfma_f32_16x16x32_bf16(a1, b1, acc[ot], 0, 0, 0);
    }
#pragma unroll
    for (int ot = 0; ot < 4; ot++)
#pragma unroll
        for (int r = 0; r < 4; r++)
            hs[(quad * 4 + r) * 256 + w * 64 + ot * 16 + m] = f2bf(acc[ot][r]);
    __syncthreads();
    {
        const int r = t >> 4, c0 = (t & 15) * 16;
        const uint4 v0 = *(const uint4*)&hs[r * 256 + c0];
        const uint4 v1 = *(const uint4*)&hs[r * 256 + c0 + 8];
        *(uint4*)&hb[(size_t)(n0 + r) * 256 + c0] = v0;
        *(uint4*)&hb[(size_t)(n0 + r) * 256 + c0 + 8] = v1;
    }
}

// ---------- K2: in-degree histogram ----------
__global__ void k_hist(const int* __restrict__ dst, int* __restrict__ degc) {
    int e = blockIdx.x * 256 + threadIdx.x;
    if (e < EE) atomicAdd(&degc[dst[e]], 1);
}

// ---------- K3: 3-kernel exclusive scan ----------
__global__ __launch_bounds__(1024) void k_scan_a(const int* __restrict__ degc, int* __restrict__ part) {
    __shared__ int sh[1024];
    int t = threadIdx.x;
    int i = blockIdx.x * SCAN_BLK + t;
    sh[t] = (i < NN) ? degc[i] : 0;
    __syncthreads();
    for (int off = 512; off > 0; off >>= 1) {
        if (t < off) sh[t] += sh[t + off];
        __syncthreads();
    }
    if (t == 0) part[blockIdx.x] = sh[0];
}

__global__ __launch_bounds__(128) void k_scan_b(int* part) {
    __shared__ int sh[128];
    int t = threadIdx.x;
    int v = (t < SCAN_NBLK) ? part[t] : 0;
    sh[t] = v;
    __syncthreads();
    for (int off = 1; off < 128; off <<= 1) {
        int tmp = (t >= off) ? sh[t - off] : 0;
        __syncthreads();
        sh[t] += tmp;
        __syncthreads();
    }
    if (t < SCAN_NBLK) part[t] = sh[t] - v;   // exclusive
}

__global__ __launch_bounds__(1024) void k_scan_c(
    const int* __restrict__ degc, const int* __restrict__ part,
    int* __restrict__ rows, int* __restrict__ curs, float* __restrict__ degf)
{
    __shared__ int sh[1024];
    int t = threadIdx.x;
    int i = blockIdx.x * SCAN_BLK + t;
    int v = (i < NN) ? degc[i] : 0;
    sh[t] = v;
    __syncthreads();
    for (int off = 1; off < 1024; off <<= 1) {
        int tmp = (t >= off) ? sh[t - off] : 0;
        __syncthreads();
        sh[t] += tmp;
        __syncthreads();
    }
    int excl = sh[t] - v + part[blockIdx.x];
    if (i < NN) {
        rows[i] = excl;
        curs[i] = excl;
        degf[i] = (float)max(v, 1);
    }
}

// ---------- K4: scatter edges into CSR (by dst) ----------
__global__ void k_scatter(const int* __restrict__ src, const int* __restrict__ dst,
                          int* __restrict__ curs, int* __restrict__ csrs) {
    int e = blockIdx.x * 256 + threadIdx.x;
    if (e < EE) {
        int d = dst[e];
        int pos = atomicAdd(&curs[d], 1);
        csrs[pos] = src[e];
    }
}

// ---------- K5: attention; unrolled 8-wide gather; bf16 out into d_out slots ----
__global__ __launch_bounds__(256) void k_attn(
    const unsigned short* __restrict__ hb,
    const float* __restrict__ ssrc, const float* __restrict__ sdst,
    const int* __restrict__ rows, const int* __restrict__ degc,
    const int* __restrict__ csrs, char* __restrict__ outb)
{
    const int lane = threadIdx.x & 63;
    const int n = blockIdx.x * 4 + (threadIdx.x >> 6);
    if (n >= NN) return;
    const int start = rows[n], cnt = degc[n];
    const int hh = lane >> 4, c = lane & 15;
    const int hsel = lane & 48;   // shfl source base: head group's 16 lanes
    float4 acc = {0.f, 0.f, 0.f, 0.f};
    if (cnt > 0) {
        const float4 sd = *(const float4*)&sdst[n * 4];
        float den = 0.f;
        for (int base = 0; base < cnt; base += 16) {
            const int j = base + c;
            int sj = 0; float exsel = 0.f;
            if (j < cnt) {
                sj = csrs[start + j];
                const float4 ss = *(const float4*)&ssrc[sj * 4];
                const float e0 = __expf(lrelu(ss.x + sd.x));
                const float e1 = __expf(lrelu(ss.y + sd.y));
                const float e2 = __expf(lrelu(ss.z + sd.z));
                const float e3 = __expf(lrelu(ss.w + sd.w));
                exsel = (hh == 0) ? e0 : (hh == 1) ? e1 : (hh == 2) ? e2 : e3;
            }
            den += exsel;
            // 8 gathers in flight; zero-padded slots (exsel=0, sj=0) are harmless
#pragma unroll
            for (int jj = 0; jj < 8; jj++) {
                const int   s = __shfl(sj,    hsel + jj);
                const float a = __shfl(exsel, hsel + jj);
                const uint2 u = *(const uint2*)&hb[(size_t)s * HO + lane * 4];
                acc.x += a * bflo(u.x);
                acc.y += a * bfhi(u.x);
                acc.z += a * bflo(u.y);
                acc.w += a * bfhi(u.y);
            }
            if (cnt - base > 8) {
#pragma unroll
                for (int jj = 8; jj < 16; jj++) {
                    const int   s = __shfl(sj,    hsel + jj);
                    const float a = __shfl(exsel, hsel + jj);
                    const uint2 u = *(const uint2*)&hb[(size_t)s * HO + lane * 4];
                    acc.x += a * bflo(u.x);
                    acc.y += a * bfhi(u.x);
                    acc.z += a * bflo(u.y);
                    acc.w += a * bfhi(u.y);
                }
            }
        }
        den += __shfl_xor(den, 1);
        den += __shfl_xor(den, 2);
        den += __shfl_xor(den, 4);
        den += __shfl_xor(den, 8);
        const float inv = 1.f / den;
        acc.x *= inv; acc.y *= inv; acc.z *= inv; acc.w *= inv;
    }
#pragma unroll
    for (int off = 16; off < 64; off <<= 1) {
        acc.x += __shfl_xor(acc.x, off);
        acc.y += __shfl_xor(acc.y, off);
        acc.z += __shfl_xor(acc.z, off);
        acc.w += __shfl_xor(acc.w, off);
    }
    if (lane < 16) {
        uint2 p;
        p.x = (unsigned int)f2bf(acc.x * 0.25f) | ((unsigned int)f2bf(acc.y * 0.25f) << 16);
        p.y = (unsigned int)f2bf(acc.z * 0.25f) | ((unsigned int)f2bf(acc.w * 0.25f) << 16);
        *(uint2*)(outb + (size_t)n * 256 + lane * 8) = p;
    }
}

// ---------- K6/K7: one mean hop — 8 lanes per edge row, 8 edges per wave instr ---
__global__ __launch_bounds__(256) void k_hop(
    const unsigned short* __restrict__ xin, const int* __restrict__ rows,
    const int* __restrict__ degc, const float* __restrict__ degf,
    const int* __restrict__ csrs, unsigned short* __restrict__ out_b)
{
    const int lane = threadIdx.x & 63;
    const int n = blockIdx.x * 4 + (threadIdx.x >> 6);
    if (n >= NN) return;
    const int start = rows[n], cnt = degc[n];
    const int g = lane >> 3;          // edge-slot group 0..7
    const int c8 = (lane & 7) * 8;    // this lane's 8-column chunk
    float a0=0.f,a1=0.f,a2=0.f,a3=0.f,a4=0.f,a5=0.f,a6=0.f,a7=0.f;
    for (int j = g; j < cnt; j += 8) {
        const int s = csrs[start + j];
        const uint4 u = *(const uint4*)&xin[(size_t)s * 64 + c8];
        a0 += bflo(u.x); a1 += bfhi(u.x);
        a2 += bflo(u.y); a3 += bfhi(u.y);
        a4 += bflo(u.z); a5 += bfhi(u.z);
        a6 += bflo(u.w); a7 += bfhi(u.w);
    }
#pragma unroll
    for (int off = 8; off < 64; off <<= 1) {
        a0 += __shfl_xor(a0, off); a1 += __shfl_xor(a1, off);
        a2 += __shfl_xor(a2, off); a3 += __shfl_xor(a3, off);
        a4 += __shfl_xor(a4, off); a5 += __shfl_xor(a5, off);
        a6 += __shfl_xor(a6, off); a7 += __shfl_xor(a7, off);
    }
    if (lane < 8) {
        const float inv = 1.f / degf[n];
        uint4 p;
        p.x = (unsigned int)f2bf(a0 * inv) | ((unsigned int)f2bf(a1 * inv) << 16);
        p.y = (unsigned int)f2bf(a2 * inv) | ((unsigned int)f2bf(a3 * inv) << 16);
        p.z = (unsigned int)f2bf(a4 * inv) | ((unsigned int)f2bf(a5 * inv) << 16);
        p.w = (unsigned int)f2bf(a6 * inv) | ((unsigned int)f2bf(a7 * inv) << 16);
        *(uint4*)&out_b[(size_t)n * 64 + c8] = p;
    }
}

// ---------- K8: build bf16 Wcat[c][k] = [Ww_top ; Wg@Ww_bot]^T, bc ----------
__global__ __launch_bounds__(1024) void k_wcomb(
    const float* __restrict__ Wg, const float* __restrict__ bg,
    const float* __restrict__ Ww, const float* __restrict__ bw,
    unsigned short* __restrict__ Wcat, float* __restrict__ bc)
{
    __shared__ float WcF[64 * 64];
    const int t = threadIdx.x;
    for (int idx = t; idx < 4096; idx += 1024) {
        const int b = idx >> 6, c = idx & 63;
        float a = 0.f;
        for (int m = 0; m < 64; m++) a += Wg[b * 64 + m] * Ww[(64 + m) * 64 + c];
        WcF[idx] = a;
    }
    if (t < 64) {
        float a = bw[t];
        for (int m = 0; m < 64; m++) a += bg[m] * Ww[(64 + m) * 64 + t];
        bc[t] = a;
    }
    __syncthreads();
    for (int idx = t; idx < 8192; idx += 1024) {
        const int c = idx >> 7, k = idx & 127;
        const float v = (k < 64) ? Ww[k * 64 + c] : WcF[(k - 64) * 64 + c];
        Wcat[idx] = f2bf(v);
    }
}

// ---------- K9: MFMA out = cat(localb,hop2b) @ Wcat + bc; 64 nodes/block -------
__global__ __launch_bounds__(256) void k_final(
    const unsigned short* __restrict__ Wcat, const float* __restrict__ bc,
    const unsigned short* __restrict__ hop2b, float* __restrict__ outp)
{
    __shared__ float os[64 * 68];   // stride 68 words: 2-way-max bank aliasing
    __shared__ float bcl[64];
    const int t = threadIdx.x;
    const int n0 = blockIdx.x * 64;
    if (t < 64) bcl[t] = bc[t];
    const int w = t >> 6, lane = t & 63, m = lane & 15, quad = lane >> 4;
    const int node = n0 + w * 16 + m;
    const int nld = min(node, NN - 1);
    const unsigned short* lrow = (const unsigned short*)((const char*)outp + (size_t)nld * 256);
    const unsigned short* grow = &hop2b[(size_t)nld * 64];
    const bf16x8 a0 = *(const bf16x8*)&lrow[quad * 8];
    const bf16x8 a1 = *(const bf16x8*)&lrow[32 + quad * 8];
    const bf16x8 a2 = *(const bf16x8*)&grow[quad * 8];
    const bf16x8 a3 = *(const bf16x8*)&grow[32 + quad * 8];
    f32x4 acc[4] = {{0.f,0.f,0.f,0.f},{0.f,0.f,0.f,0.f},{0.f,0.f,0.f,0.f},{0.f,0.f,0.f,0.f}};
#pragma unroll
    for (int ot = 0; ot < 4; ot++) {
        const unsigned short* wp = Wcat + (ot * 16 + m) * 128 + quad * 8;
        const bf16x8 b0 = *(const bf16x8*)wp;
        const bf16x8 b1 = *(const bf16x8*)(wp + 32);
        const bf16x8 b2 = *(const bf16x8*)(wp + 64);
        const bf16x8 b3 = *(const bf16x8*)(wp + 96);
        acc[ot] = __builtin_amdgcn_mfma_f32_16x16x32_bf16(a0, b0, acc[ot], 0, 0, 0);
        acc[ot] = __builtin_amdgcn_mfma_f32_16x16x32_bf16(a1, b1, acc[ot], 0, 0, 0);
        acc[ot] = __builtin_amdgcn_mfma_f32_16x16x32_bf16(a2, b2, acc[ot], 0, 0, 0);
        acc[ot] = __builtin_amdgcn_mfma_f32_16x16x32_bf16(a3, b3, acc[ot], 0, 0, 0);
    }
    __syncthreads();   // bcl ready; also orders global a-loads before the stores below
#pragma unroll
    for (int ot = 0; ot < 4; ot++)
#pragma unroll
        for (int r = 0; r < 4; r++)
            os[(w * 16 + quad * 4 + r) * 68 + ot * 16 + m] = acc[ot][r] + bcl[ot * 16 + m];
    __syncthreads();
#pragma unroll
    for (int p = 0; p < 4; p++) {
        const int idx = p * 256 + t;
        const int row = idx >> 4, f4 = idx & 15;
        if (n0 + row < NN)
            *(float4*)&outp[(size_t)(n0 + row) * 64 + f4 * 4] = *(const float4*)&os[row * 68 + f4 * 4];
    }
}

extern "C" void kernel_launch(void* const* d_in, const int* in_sizes, int n_in,
                              void* d_out, int out_size, void* d_ws, size_t ws_size,
                              hipStream_t stream)
{
    const float* x    = (const float*)d_in[0];
    const int*   ei   = (const int*)d_in[1];
    const int*   srcp = ei;
    const int*   dstp = ei + EE;
    const float* Watt = (const float*)d_in[2];
    const float* asrc = (const float*)d_in[3];
    const float* adst = (const float*)d_in[4];
    const float* Wg   = (const float*)d_in[5];
    const float* bg   = (const float*)d_in[6];
    const float* Ww   = (const float*)d_in[7];
    const float* bw   = (const float*)d_in[8];
    float* outp = (float*)d_out;

    if (ws_size < WS_NEEDED) return;   // fail loudly (validation will catch)

    char* ws = (char*)d_ws;
    unsigned short* hb    = (unsigned short*)(ws + OFF_H);
    unsigned short* hop1  = (unsigned short*)(ws + OFF_HOP1);  // aliases hb (dead)
    unsigned short* hop2b = (unsigned short*)(ws + OFF_HOP2);  // inside dead hb
    unsigned short* xb    = (unsigned short*)(ws + OFF_XB);
    float* ssrc = (float*)(ws + OFF_SSRC);
    float* sdst = (float*)(ws + OFF_SDST);
    int*   degc = (int*)(ws + OFF_DEGC);
    int*   rows = (int*)(ws + OFF_ROWS);
    int*   curs = (int*)(ws + OFF_CURS);
    float* degf = (float*)(ws + OFF_DEGF);
    int*   part = (int*)(ws + OFF_PART);
    int*   csrs = (int*)(ws + OFF_CSRS);
    unsigned short* Wcat = (unsigned short*)(ws + OFF_WCAT);
    float* bc   = (float*)(ws + OFF_BCOMB);
    unsigned short* Wt = (unsigned short*)(ws + OFF_WT);
    float* waS  = (float*)(ws + OFF_WAS);
    float* waD  = (float*)(ws + OFF_WAD);

    hipMemsetAsync(degc, 0, NN * sizeof(int), stream);
    k_prep<<<1, 256, 0, stream>>>(Watt, asrc, adst, Wt, waS, waD);
    k_hist<<<(EE + 255) / 256, 256, 0, stream>>>(dstp, degc);
    k_scan_a<<<SCAN_NBLK, 1024, 0, stream>>>(degc, part);
    k_scan_b<<<1, 128, 0, stream>>>(part);
    k_scan_c<<<SCAN_NBLK, 1024, 0, stream>>>(degc, part, rows, curs, degf);
    k_scatter<<<(EE + 255) / 256, 256, 0, stream>>>(srcp, dstp, curs, csrs);
    k_h<<<NN / 16, 256, 0, stream>>>(x, Wt, waS, waD, hb, xb, ssrc, sdst);
    k_attn<<<NN / 4, 256, 0, stream>>>(hb, ssrc, sdst, rows, degc, csrs, (char*)d_out);
    k_hop<<<NN / 4, 256, 0, stream>>>(xb, rows, degc, degf, csrs, hop1);
    k_hop<<<NN / 4, 256, 0, stream>>>(hop1, rows, degc, degf, csrs, hop2b);
    k_wcomb<<<1, 1024, 0, stream>>>(Wg, bg, Ww, bw, Wcat, bc);
    k_final<<<(NN + 63) / 64, 256, 0, stream>>>(Wcat, bc, hop2b, outp);
}

// Round 7
// 329.261 us; speedup vs baseline: 1.7610x; 1.2748x over previous
//
#include <hip/hip_runtime.h>
#include <math.h>

#define NN 100000
#define EE 800000
#define FDIM 64
#define NH 4
#define NEG 0.2f

#define SCAN_BLK 1024
#define SCAN_NBLK 98      // ceil(100000/1024)

// ---------- workspace layout (bytes) ----------
#define OFF_XB     0ull                       // bf16 x: 12.8 MB
#define OFF_HOP1   12800000ull                // bf16 hop1: 12.8 MB
#define OFF_HOP2   25600000ull                // bf16 hop2: 12.8 MB
#define OFF_SSRC   38400000ull                // N*4 fp32
#define OFF_SDST   40000000ull
#define OFF_DEGC   41600000ull                // N int
#define OFF_ROWS   42000000ull
#define OFF_CURS   42400000ull
#define OFF_DEGF   42800000ull
#define OFF_PART   43200000ull
#define OFF_CSRS   43201024ull                // E int
#define OFF_WCAT   46401024ull                // bf16 Wcat[64][128] = 16384 B
#define OFF_BCOMB  46417408ull                // fp32 bc[64]
#define OFF_WT     46417664ull                // bf16 Wt[h][o][k]: 32768 B
#define OFF_WAS    46450432ull                // fp32 waS[4][64]
#define OFF_WAD    46451456ull                // fp32 waD[4][64]
#define WS_NEEDED  46452480ull

typedef __attribute__((ext_vector_type(8))) short bf16x8;
typedef __attribute__((ext_vector_type(4))) float f32x4;

__device__ __forceinline__ float bflo(unsigned int u) { return __uint_as_float(u << 16); }
__device__ __forceinline__ float bfhi(unsigned int u) { return __uint_as_float(u & 0xffff0000u); }
__device__ __forceinline__ unsigned short f2bf(float f) {
    unsigned int u = __float_as_uint(f);
    unsigned int r = u + 0x7fffu + ((u >> 16) & 1u);   // RNE
    return (unsigned short)(r >> 16);
}
__device__ __forceinline__ float lrelu(float x) { return x > 0.f ? x : NEG * x; }

// ---------- K0: prep — Wt[h][o][k]=bf16(Watt[h][k][o]); waS/waD folds ----------
__global__ __launch_bounds__(256) void k_prep(
    const float* __restrict__ Watt, const float* __restrict__ asrc,
    const float* __restrict__ adst,
    unsigned short* __restrict__ Wt, float* __restrict__ waS, float* __restrict__ waD)
{
    const int t = threadIdx.x;
    const int b = blockIdx.x;
    for (int idx = b * 2048 + t; idx < (b + 1) * 2048; idx += 256) {
        const int h = idx >> 12, o = (idx >> 6) & 63, k = idx & 63;
        Wt[idx] = f2bf(Watt[h * 4096 + k * 64 + o]);
    }
    if (b == 0) {
        const int h = t >> 6, i = t & 63;
        float aS = 0.f, aD = 0.f;
        for (int o = 0; o < 64; o++) {
            const float w = Watt[h * 4096 + i * 64 + o];
            aS += w * asrc[h * 64 + o];
            aD += w * adst[h * 64 + o];
        }
        waS[t] = aS;
        waD[t] = aD;
    }
}

// ---------- K1: xb emit + scores ssrc/sdst (no h materialization!) ----------
__global__ __launch_bounds__(256) void k_h(
    const float* __restrict__ x, const float* __restrict__ waS, const float* __restrict__ waD,
    unsigned short* __restrict__ xb, float* __restrict__ ssrc, float* __restrict__ sdst)
{
    __shared__ float xs[16 * 64];
    __shared__ unsigned short xsb[16 * 64];
    __shared__ float wl[2 * 256];
    const int t = threadIdx.x;
    const int n0 = blockIdx.x * 16;
    {
        const int r = t >> 4, c4 = (t & 15) * 4;
        const float4 v = *(const float4*)&x[(size_t)(n0 + r) * 64 + c4];
        *(float4*)&xs[r * 64 + c4] = v;
        uint2 p;
        p.x = (unsigned int)f2bf(v.x) | ((unsigned int)f2bf(v.y) << 16);
        p.y = (unsigned int)f2bf(v.z) | ((unsigned int)f2bf(v.w) << 16);
        *(uint2*)&xsb[r * 64 + c4] = p;
        wl[t] = waS[t];
        wl[256 + t] = waD[t];
    }
    __syncthreads();
    if (t < 128) {
        const int r = t >> 3, c8 = (t & 7) * 8;
        const uint4 v = *(const uint4*)&xsb[r * 64 + c8];
        *(uint4*)&xb[(size_t)(n0 + r) * 64 + c8] = v;
    }
    {
        const int nl = t >> 4, hh = (t >> 2) & 3, q = t & 3;
        const float* xr = &xs[nl * 64 + q * 16];
        const float* wS = &wl[hh * 64 + q * 16];
        const float* wD = &wl[256 + hh * 64 + q * 16];
        float pS = 0.f, pD = 0.f;
#pragma unroll
        for (int i = 0; i < 16; i++) { pS += xr[i] * wS[i]; pD += xr[i] * wD[i]; }
        pS += __shfl_xor(pS, 1); pS += __shfl_xor(pS, 2);
        pD += __shfl_xor(pD, 1); pD += __shfl_xor(pD, 2);
        if (q == 0) {
            ssrc[(n0 + nl) * 4 + hh] = pS;
            sdst[(n0 + nl) * 4 + hh] = pD;
        }
    }
}

// ---------- K2: in-degree histogram ----------
__global__ void k_hist(const int* __restrict__ dst, int* __restrict__ degc) {
    int e = blockIdx.x * 256 + threadIdx.x;
    if (e < EE) atomicAdd(&degc[dst[e]], 1);
}

// ---------- K3: 3-kernel exclusive scan ----------
__global__ __launch_bounds__(1024) void k_scan_a(const int* __restrict__ degc, int* __restrict__ part) {
    __shared__ int sh[1024];
    int t = threadIdx.x;
    int i = blockIdx.x * SCAN_BLK + t;
    sh[t] = (i < NN) ? degc[i] : 0;
    __syncthreads();
    for (int off = 512; off > 0; off >>= 1) {
        if (t < off) sh[t] += sh[t + off];
        __syncthreads();
    }
    if (t == 0) part[blockIdx.x] = sh[0];
}

__global__ __launch_bounds__(128) void k_scan_b(int* part) {
    __shared__ int sh[128];
    int t = threadIdx.x;
    int v = (t < SCAN_NBLK) ? part[t] : 0;
    sh[t] = v;
    __syncthreads();
    for (int off = 1; off < 128; off <<= 1) {
        int tmp = (t >= off) ? sh[t - off] : 0;
        __syncthreads();
        sh[t] += tmp;
        __syncthreads();
    }
    if (t < SCAN_NBLK) part[t] = sh[t] - v;   // exclusive
}

__global__ __launch_bounds__(1024) void k_scan_c(
    const int* __restrict__ degc, const int* __restrict__ part,
    int* __restrict__ rows, int* __restrict__ curs, float* __restrict__ degf)
{
    __shared__ int sh[1024];
    int t = threadIdx.x;
    int i = blockIdx.x * SCAN_BLK + t;
    int v = (i < NN) ? degc[i] : 0;
    sh[t] = v;
    __syncthreads();
    for (int off = 1; off < 1024; off <<= 1) {
        int tmp = (t >= off) ? sh[t - off] : 0;
        __syncthreads();
        sh[t] += tmp;
        __syncthreads();
    }
    int excl = sh[t] - v + part[blockIdx.x];
    if (i < NN) {
        rows[i] = excl;
        curs[i] = excl;
        degf[i] = (float)max(v, 1);
    }
}

// ---------- K4: scatter edges into CSR (by dst) ----------
__global__ void k_scatter(const int* __restrict__ src, const int* __restrict__ dst,
                          int* __restrict__ curs, int* __restrict__ csrs) {
    int e = blockIdx.x * 256 + threadIdx.x;
    if (e < EE) {
        int d = dst[e];
        int pos = atomicAdd(&curs[d], 1);
        csrs[pos] = src[e];
    }
}

// ---------- K5: fused attention+hop1 gather on x, then per-head MFMA ------------
// wave: 4 nodes x 2 edge-slots x 8 col-lanes. Weighted sums y_h = sum ex_h*x[s],
// hop = sum x[s]; then block MFMA (wave w = head w): local = mean_h(Y_h @ W_h).
__global__ __launch_bounds__(256) void k_attn2(
    const unsigned short* __restrict__ xb, const unsigned short* __restrict__ Wt,
    const float* __restrict__ ssrc, const float* __restrict__ sdst,
    const int* __restrict__ rows, const int* __restrict__ degc,
    const float* __restrict__ degf, const int* __restrict__ csrs,
    unsigned short* __restrict__ hop1b, char* __restrict__ outb)
{
    __shared__ unsigned short ysh[4 * 16 * 64];   // [head][node][col] bf16
    __shared__ float dsh[4][16][66];              // [head][node][col] fp32 (padded)
    const int t = threadIdx.x;
    const int w = t >> 6, lane = t & 63;
    const int nl = (lane >> 4) & 3;
    const int e  = (lane >> 3) & 1;
    const int cl = lane & 7;
    const int n = blockIdx.x * 16 + w * 4 + nl;
    const int start = rows[n], cnt = degc[n];
    int cmax = cnt;
    cmax = max(cmax, __shfl_xor(cmax, 16));
    cmax = max(cmax, __shfl_xor(cmax, 32));
    const float4 sd = *(const float4*)&sdst[n * 4];
    float y0[8], y1[8], y2[8], y3[8], hp[8];
#pragma unroll
    for (int c = 0; c < 8; c++) { y0[c]=0.f; y1[c]=0.f; y2[c]=0.f; y3[c]=0.f; hp[c]=0.f; }
    float d0 = 0.f, d1 = 0.f, d2 = 0.f, d3 = 0.f;
    for (int base = 0; base < cmax; base += 2) {
        const int j = base + e;
        const bool valid = j < cnt;
        const int idx = min(start + j, EE - 1);
        const int s = csrs[idx];
        const float4 ss = *(const float4*)&ssrc[s * 4];
        float e0 = __expf(lrelu(ss.x + sd.x));
        float e1 = __expf(lrelu(ss.y + sd.y));
        float e2 = __expf(lrelu(ss.z + sd.z));
        float e3 = __expf(lrelu(ss.w + sd.w));
        float hw = 1.f;
        if (!valid) { e0 = 0.f; e1 = 0.f; e2 = 0.f; e3 = 0.f; hw = 0.f; }
        d0 += e0; d1 += e1; d2 += e2; d3 += e3;
        const uint4 u = *(const uint4*)&xb[(size_t)s * 64 + cl * 8];
        float xv[8];
        xv[0] = bflo(u.x); xv[1] = bfhi(u.x);
        xv[2] = bflo(u.y); xv[3] = bfhi(u.y);
        xv[4] = bflo(u.z); xv[5] = bfhi(u.z);
        xv[6] = bflo(u.w); xv[7] = bfhi(u.w);
#pragma unroll
        for (int c = 0; c < 8; c++) {
            y0[c] += e0 * xv[c];
            y1[c] += e1 * xv[c];
            y2[c] += e2 * xv[c];
            y3[c] += e3 * xv[c];
            hp[c] += hw * xv[c];
        }
    }
    // reduce over edge-slot bit (xor 8)
#pragma unroll
    for (int c = 0; c < 8; c++) {
        y0[c] += __shfl_xor(y0[c], 8);
        y1[c] += __shfl_xor(y1[c], 8);
        y2[c] += __shfl_xor(y2[c], 8);
        y3[c] += __shfl_xor(y3[c], 8);
        hp[c] += __shfl_xor(hp[c], 8);
    }
    d0 += __shfl_xor(d0, 8);
    d1 += __shfl_xor(d1, 8);
    d2 += __shfl_xor(d2, 8);
    d3 += __shfl_xor(d3, 8);
    if (e == 0) {
        const float i0 = (cnt > 0) ? 1.f / d0 : 0.f;
        const float i1 = (cnt > 0) ? 1.f / d1 : 0.f;
        const float i2 = (cnt > 0) ? 1.f / d2 : 0.f;
        const float i3 = (cnt > 0) ? 1.f / d3 : 0.f;
        const int nloc = w * 4 + nl;
        uint4 p;
        p.x = (unsigned int)f2bf(y0[0]*i0) | ((unsigned int)f2bf(y0[1]*i0) << 16);
        p.y = (unsigned int)f2bf(y0[2]*i0) | ((unsigned int)f2bf(y0[3]*i0) << 16);
        p.z = (unsigned int)f2bf(y0[4]*i0) | ((unsigned int)f2bf(y0[5]*i0) << 16);
        p.w = (unsigned int)f2bf(y0[6]*i0) | ((unsigned int)f2bf(y0[7]*i0) << 16);
        *(uint4*)&ysh[0 * 1024 + nloc * 64 + cl * 8] = p;
        p.x = (unsigned int)f2bf(y1[0]*i1) | ((unsigned int)f2bf(y1[1]*i1) << 16);
        p.y = (unsigned int)f2bf(y1[2]*i1) | ((unsigned int)f2bf(y1[3]*i1) << 16);
        p.z = (unsigned int)f2bf(y1[4]*i1) | ((unsigned int)f2bf(y1[5]*i1) << 16);
        p.w = (unsigned int)f2bf(y1[6]*i1) | ((unsigned int)f2bf(y1[7]*i1) << 16);
        *(uint4*)&ysh[1 * 1024 + nloc * 64 + cl * 8] = p;
        p.x = (unsigned int)f2bf(y2[0]*i2) | ((unsigned int)f2bf(y2[1]*i2) << 16);
        p.y = (unsigned int)f2bf(y2[2]*i2) | ((unsigned int)f2bf(y2[3]*i2) << 16);
        p.z = (unsigned int)f2bf(y2[4]*i2) | ((unsigned int)f2bf(y2[5]*i2) << 16);
        p.w = (unsigned int)f2bf(y2[6]*i2) | ((unsigned int)f2bf(y2[7]*i2) << 16);
        *(uint4*)&ysh[2 * 1024 + nloc * 64 + cl * 8] = p;
        p.x = (unsigned int)f2bf(y3[0]*i3) | ((unsigned int)f2bf(y3[1]*i3) << 16);
        p.y = (unsigned int)f2bf(y3[2]*i3) | ((unsigned int)f2bf(y3[3]*i3) << 16);
        p.z = (unsigned int)f2bf(y3[4]*i3) | ((unsigned int)f2bf(y3[5]*i3) << 16);
        p.w = (unsigned int)f2bf(y3[6]*i3) | ((unsigned int)f2bf(y3[7]*i3) << 16);
        *(uint4*)&ysh[3 * 1024 + nloc * 64 + cl * 8] = p;
        const float iv = 1.f / degf[n];
        p.x = (unsigned int)f2bf(hp[0]*iv) | ((unsigned int)f2bf(hp[1]*iv) << 16);
        p.y = (unsigned int)f2bf(hp[2]*iv) | ((unsigned int)f2bf(hp[3]*iv) << 16);
        p.z = (unsigned int)f2bf(hp[4]*iv) | ((unsigned int)f2bf(hp[5]*iv) << 16);
        p.w = (unsigned int)f2bf(hp[6]*iv) | ((unsigned int)f2bf(hp[7]*iv) << 16);
        *(uint4*)&hop1b[(size_t)n * 64 + cl * 8] = p;
    }
    __syncthreads();
    // MFMA: wave w computes head w: D[16 nodes x 64] = Y_w @ W_w
    {
        const int m = lane & 15, quad = lane >> 4;
        const bf16x8 a0 = *(const bf16x8*)&ysh[w * 1024 + m * 64 + quad * 8];
        const bf16x8 a1 = *(const bf16x8*)&ysh[w * 1024 + m * 64 + 32 + quad * 8];
        f32x4 acc[4] = {{0.f,0.f,0.f,0.f},{0.f,0.f,0.f,0.f},{0.f,0.f,0.f,0.f},{0.f,0.f,0.f,0.f}};
#pragma unroll
        for (int ot = 0; ot < 4; ot++) {
            const unsigned short* wp = Wt + w * 4096 + (ot * 16 + m) * 64 + quad * 8;
            const bf16x8 b0 = *(const bf16x8*)wp;
            const bf16x8 b1 = *(const bf16x8*)(wp + 32);
            acc[ot] = __builtin_amdgcn_mfma_f32_16x16x32_bf16(a0, b0, acc[ot], 0, 0, 0);
            acc[ot] = __builtin_amdgcn_mfma_f32_16x16x32_bf16(a1, b1, acc[ot], 0, 0, 0);
        }
#pragma unroll
        for (int ot = 0; ot < 4; ot++)
#pragma unroll
            for (int r = 0; r < 4; r++)
                dsh[w][quad * 4 + r][ot * 16 + m] = acc[ot][r];
    }
    __syncthreads();
    // head mean -> bf16 local into first 128B of each 256B d_out slot
    {
        const int n2 = t >> 4, c4 = (t & 15) * 4;
        float o0 = 0.25f * (dsh[0][n2][c4+0] + dsh[1][n2][c4+0] + dsh[2][n2][c4+0] + dsh[3][n2][c4+0]);
        float o1 = 0.25f * (dsh[0][n2][c4+1] + dsh[1][n2][c4+1] + dsh[2][n2][c4+1] + dsh[3][n2][c4+1]);
        float o2 = 0.25f * (dsh[0][n2][c4+2] + dsh[1][n2][c4+2] + dsh[2][n2][c4+2] + dsh[3][n2][c4+2]);
        float o3 = 0.25f * (dsh[0][n2][c4+3] + dsh[1][n2][c4+3] + dsh[2][n2][c4+3] + dsh[3][n2][c4+3]);
        uint2 p;
        p.x = (unsigned int)f2bf(o0) | ((unsigned int)f2bf(o1) << 16);
        p.y = (unsigned int)f2bf(o2) | ((unsigned int)f2bf(o3) << 16);
        *(uint2*)(outb + ((size_t)(blockIdx.x * 16 + n2)) * 256 + (t & 15) * 8) = p;
    }
}

// ---------- K6: second mean hop — 8 lanes per edge row ----------
__global__ __launch_bounds__(256) void k_hop(
    const unsigned short* __restrict__ xin, const int* __restrict__ rows,
    const int* __restrict__ degc, const float* __restrict__ degf,
    const int* __restrict__ csrs, unsigned short* __restrict__ out_b)
{
    const int lane = threadIdx.x & 63;
    const int n = blockIdx.x * 4 + (threadIdx.x >> 6);
    if (n >= NN) return;
    const int start = rows[n], cnt = degc[n];
    const int g = lane >> 3;
    const int c8 = (lane & 7) * 8;
    float a0=0.f,a1=0.f,a2=0.f,a3=0.f,a4=0.f,a5=0.f,a6=0.f,a7=0.f;
    for (int j = g; j < cnt; j += 8) {
        const int s = csrs[start + j];
        const uint4 u = *(const uint4*)&xin[(size_t)s * 64 + c8];
        a0 += bflo(u.x); a1 += bfhi(u.x);
        a2 += bflo(u.y); a3 += bfhi(u.y);
        a4 += bflo(u.z); a5 += bfhi(u.z);
        a6 += bflo(u.w); a7 += bfhi(u.w);
    }
#pragma unroll
    for (int off = 8; off < 64; off <<= 1) {
        a0 += __shfl_xor(a0, off); a1 += __shfl_xor(a1, off);
        a2 += __shfl_xor(a2, off); a3 += __shfl_xor(a3, off);
        a4 += __shfl_xor(a4, off); a5 += __shfl_xor(a5, off);
        a6 += __shfl_xor(a6, off); a7 += __shfl_xor(a7, off);
    }
    if (lane < 8) {
        const float inv = 1.f / degf[n];
        uint4 p;
        p.x = (unsigned int)f2bf(a0 * inv) | ((unsigned int)f2bf(a1 * inv) << 16);
        p.y = (unsigned int)f2bf(a2 * inv) | ((unsigned int)f2bf(a3 * inv) << 16);
        p.z = (unsigned int)f2bf(a4 * inv) | ((unsigned int)f2bf(a5 * inv) << 16);
        p.w = (unsigned int)f2bf(a6 * inv) | ((unsigned int)f2bf(a7 * inv) << 16);
        *(uint4*)&out_b[(size_t)n * 64 + c8] = p;
    }
}

// ---------- K8: build bf16 Wcat[c][k] = [Ww_top ; Wg@Ww_bot]^T, bc ----------
__global__ __launch_bounds__(1024) void k_wcomb(
    const float* __restrict__ Wg, const float* __restrict__ bg,
    const float* __restrict__ Ww, const float* __restrict__ bw,
    unsigned short* __restrict__ Wcat, float* __restrict__ bc)
{
    __shared__ float WcS[64][16];
    const int t = threadIdx.x;
    const int c0 = blockIdx.x * 16;
    {
        const int r = t >> 4, ci = t & 15;
        float a = 0.f;
        for (int m = 0; m < 64; m++) a += Wg[r * 64 + m] * Ww[(64 + m) * 64 + c0 + ci];
        WcS[r][ci] = a;
    }
    if (blockIdx.x == 0 && t < 64) {
        float a = bw[t];
        for (int m = 0; m < 64; m++) a += bg[m] * Ww[(64 + m) * 64 + t];
        bc[t] = a;
    }
    __syncthreads();
    for (int idx = t; idx < 2048; idx += 1024) {
        const int ci = idx >> 7, k = idx & 127;
        const int c = c0 + ci;
        const float v = (k < 64) ? Ww[k * 64 + c] : WcS[k - 64][ci];
        Wcat[c * 128 + k] = f2bf(v);
    }
}

// ---------- K9: MFMA out = cat(localb,hop2b) @ Wcat + bc; 64 nodes/block -------
__global__ __launch_bounds__(256) void k_final(
    const unsigned short* __restrict__ Wcat, const float* __restrict__ bc,
    const unsigned short* __restrict__ hop2b, float* __restrict__ outp)
{
    __shared__ float os[64 * 68];
    __shared__ float bcl[64];
    const int t = threadIdx.x;
    const int n0 = blockIdx.x * 64;
    if (t < 64) bcl[t] = bc[t];
    const int w = t >> 6, lane = t & 63, m = lane & 15, quad = lane >> 4;
    const int node = n0 + w * 16 + m;
    const int nld = min(node, NN - 1);
    const unsigned short* lrow = (const unsigned short*)((const char*)outp + (size_t)nld * 256);
    const unsigned short* grow = &hop2b[(size_t)nld * 64];
    const bf16x8 a0 = *(const bf16x8*)&lrow[quad * 8];
    const bf16x8 a1 = *(const bf16x8*)&lrow[32 + quad * 8];
    const bf16x8 a2 = *(const bf16x8*)&grow[quad * 8];
    const bf16x8 a3 = *(const bf16x8*)&grow[32 + quad * 8];
    f32x4 acc[4] = {{0.f,0.f,0.f,0.f},{0.f,0.f,0.f,0.f},{0.f,0.f,0.f,0.f},{0.f,0.f,0.f,0.f}};
#pragma unroll
    for (int ot = 0; ot < 4; ot++) {
        const unsigned short* wp = Wcat + (ot * 16 + m) * 128 + quad * 8;
        const bf16x8 b0 = *(const bf16x8*)wp;
        const bf16x8 b1 = *(const bf16x8*)(wp + 32);
        const bf16x8 b2 = *(const bf16x8*)(wp + 64);
        const bf16x8 b3 = *(const bf16x8*)(wp + 96);
        acc[ot] = __builtin_amdgcn_mfma_f32_16x16x32_bf16(a0, b0, acc[ot], 0, 0, 0);
        acc[ot] = __builtin_amdgcn_mfma_f32_16x16x32_bf16(a1, b1, acc[ot], 0, 0, 0);
        acc[ot] = __builtin_amdgcn_mfma_f32_16x16x32_bf16(a2, b2, acc[ot], 0, 0, 0);
        acc[ot] = __builtin_amdgcn_mfma_f32_16x16x32_bf16(a3, b3, acc[ot], 0, 0, 0);
    }
    __syncthreads();
#pragma unroll
    for (int ot = 0; ot < 4; ot++)
#pragma unroll
        for (int r = 0; r < 4; r++)
            os[(w * 16 + quad * 4 + r) * 68 + ot * 16 + m] = acc[ot][r] + bcl[ot * 16 + m];
    __syncthreads();
#pragma unroll
    for (int p = 0; p < 4; p++) {
        const int idx = p * 256 + t;
        const int row = idx >> 4, f4 = idx & 15;
        if (n0 + row < NN)
            *(float4*)&outp[(size_t)(n0 + row) * 64 + f4 * 4] = *(const float4*)&os[row * 68 + f4 * 4];
    }
}

extern "C" void kernel_launch(void* const* d_in, const int* in_sizes, int n_in,
                              void* d_out, int out_size, void* d_ws, size_t ws_size,
                              hipStream_t stream)
{
    const float* x    = (const float*)d_in[0];
    const int*   ei   = (const int*)d_in[1];
    const int*   srcp = ei;
    const int*   dstp = ei + EE;
    const float* Watt = (const float*)d_in[2];
    const float* asrc = (const float*)d_in[3];
    const float* adst = (const float*)d_in[4];
    const float* Wg   = (const float*)d_in[5];
    const float* bg   = (const float*)d_in[6];
    const float* Ww   = (const float*)d_in[7];
    const float* bw   = (const float*)d_in[8];
    float* outp = (float*)d_out;

    if (ws_size < WS_NEEDED) return;

    char* ws = (char*)d_ws;
    unsigned short* xb    = (unsigned short*)(ws + OFF_XB);
    unsigned short* hop1b = (unsigned short*)(ws + OFF_HOP1);
    unsigned short* hop2b = (unsigned short*)(ws + OFF_HOP2);
    float* ssrc = (float*)(ws + OFF_SSRC);
    float* sdst = (float*)(ws + OFF_SDST);
    int*   degc = (int*)(ws + OFF_DEGC);
    int*   rows = (int*)(ws + OFF_ROWS);
    int*   curs = (int*)(ws + OFF_CURS);
    float* degf = (float*)(ws + OFF_DEGF);
    int*   part = (int*)(ws + OFF_PART);
    int*   csrs = (int*)(ws + OFF_CSRS);
    unsigned short* Wcat = (unsigned short*)(ws + OFF_WCAT);
    float* bc   = (float*)(ws + OFF_BCOMB);
    unsigned short* Wt = (unsigned short*)(ws + OFF_WT);
    float* waS  = (float*)(ws + OFF_WAS);
    float* waD  = (float*)(ws + OFF_WAD);

    hipMemsetAsync(degc, 0, NN * sizeof(int), stream);
    k_prep<<<8, 256, 0, stream>>>(Watt, asrc, adst, Wt, waS, waD);
    k_hist<<<(EE + 255) / 256, 256, 0, stream>>>(dstp, degc);
    k_scan_a<<<SCAN_NBLK, 1024, 0, stream>>>(degc, part);
    k_scan_b<<<1, 128, 0, stream>>>(part);
    k_scan_c<<<SCAN_NBLK, 1024, 0, stream>>>(degc, part, rows, curs, degf);
    k_scatter<<<(EE + 255) / 256, 256, 0, stream>>>(srcp, dstp, curs, csrs);
    k_h<<<NN / 16, 256, 0, stream>>>(x, waS, waD, xb, ssrc, sdst);
    k_attn2<<<NN / 16, 256, 0, stream>>>(xb, Wt, ssrc, sdst, rows, degc, degf, csrs, hop1b, (char*)d_out);
    k_hop<<<NN / 4, 256, 0, stream>>>(hop1b, rows, degc, degf, csrs, hop2b);
    k_wcomb<<<4, 1024, 0, stream>>>(Wg, bg, Ww, bw, Wcat, bc);
    k_final<<<(NN + 63) / 64, 256, 0, stream>>>(Wcat, bc, hop2b, outp);
}